// Round 7
// baseline (608.218 us; speedup 1.0000x reference)
//
#include <hip/hip_runtime.h>

// RGAT: 2-layer, 2-relation GAT. N=20000, E=320000/rel, D=128, H=2.
// Round 7: (1) agg1/agg2 -> one-WAVE-per-dst with register-resident softmax
// (zero LDS, zero barriers; alpha broadcast via uniform __shfl/readlane);
// (2) dispatches 12->8: detect folded into convzero (per-block flag),
// prep+hist merged, elr1+scatter merged.

#define NN 20000
#define NE 320000

typedef unsigned short bf16_t;
typedef __attribute__((ext_vector_type(8))) short short8;
typedef __attribute__((ext_vector_type(4))) float f32x4;

__device__ __forceinline__ float bf2f(bf16_t u) {
    return __uint_as_float(((unsigned)u) << 16);
}
__device__ __forceinline__ bf16_t f2bf(float f) {
    unsigned x = __float_as_uint(f);
    unsigned r = (x + 0x7fffu + ((x >> 16) & 1u)) >> 16;   // RNE
    return (bf16_t)r;
}
__device__ __forceinline__ float lrelu(float v) {
    return (v > 0.f) ? v : 0.2f * v;
}

// ------------- convert 17 float tensors to bf16 + zero region ---------------
// dtype flag (fp32 vs bf16 source) derived PER BLOCK from x's first 256 words
// (low halves as bf16 are astronomically large iff source is fp32), so no
// separate detect dispatch; block 0 persists it for gemm2.
#define NT 17
struct CzArgs {
    const void* src[NT];
    bf16_t* dst[NT];
    int n[NT];
    int nblk[NT + 1];     // blocks per segment; last = zero segment
    int* zero_ptr;
    int zn;
    const unsigned* xsrc;
    int* flag_out;
};
__global__ void convzero_kernel(CzArgs a) {
    __shared__ int fl_s;
    int t = threadIdx.x;
    if (t < 64) {
        float mx = 0.f;
        for (int i = t; i < 256; i += 64) {
            float v = fabsf(bf2f((bf16_t)(a.xsrc[i] & 0xffffu)));
            v = (v <= 1e30f) ? v : 1e30f;
            mx = fmaxf(mx, v);
        }
        for (int off = 32; off > 0; off >>= 1) mx = fmaxf(mx, __shfl_xor(mx, off));
        if (t == 0) {
            int f = (mx > 1e6f) ? 1 : 0;
            fl_s = f;
            if (blockIdx.x == 0) *a.flag_out = f;
        }
    }
    __syncthreads();
    int flag = fl_s;
    int b = blockIdx.x;
    int ti = 0;
#pragma unroll 1
    for (; ti <= NT; ++ti) {
        if (b < a.nblk[ti]) break;
        b -= a.nblk[ti];
    }
    int i = b * 256 + t;
    if (ti < NT) {
        if (i < a.n[ti]) {
            if (flag) a.dst[ti][i] = f2bf(((const float*)a.src[ti])[i]);
            else      a.dst[ti][i] = ((const bf16_t*)a.src[ti])[i];
        }
    } else {
        if (i < a.zn) a.zero_ptr[i] = 0;
    }
}

// ---------------- prep: wal/war vectors, combined biases, Wc frag repack ----
struct PrepArgs {
    const bf16_t *W1[2], *W2[2];
    const bf16_t *al1[2], *ar1[2], *al2[2], *ar2[2];
    const bf16_t *b1[2], *b2[2];
    float *wal1, *war1;     // [2rel*2h*128]
    float *wal2, *war2;     // [2rel*2h*256]
    float *bc1, *bc2;       // [256], [128]
    bf16_t *Wc1f, *Wc2f;    // frag-order combined weights
};
// bx: [0,4) wal1/war1 | [4,12) wal2/war2 | [12,14) bc | [14,78) Wc1f | [78,142) Wc2f
__device__ __forceinline__ void prep_body(const PrepArgs& p, int bx, int tid) {
    if (bx < 4) {
        int t = bx * 256 + tid;
        int lr = t >> 9, rel = (t >> 8) & 1, h = (t >> 7) & 1, k = t & 127;
        const bf16_t* av = lr ? p.ar1[rel] : p.al1[rel];
        const bf16_t* W = p.W1[rel];
        float s = 0.f;
        for (int o = 0; o < 256; ++o)
            s += bf2f(W[k * 512 + h * 256 + o]) * bf2f(av[h * 256 + o]);
        (lr ? p.war1 : p.wal1)[(rel * 2 + h) * 128 + k] = s;
    } else if (bx < 12) {
        int t = (bx - 4) * 256 + tid;
        int lr = t >> 10, rel = (t >> 9) & 1, h = (t >> 8) & 1, k = t & 255;
        const bf16_t* av = lr ? p.ar2[rel] : p.al2[rel];
        const bf16_t* W = p.W2[rel];
        float s = 0.f;
        for (int o = 0; o < 128; ++o)
            s += bf2f(W[k * 256 + h * 128 + o]) * bf2f(av[h * 128 + o]);
        (lr ? p.war2 : p.wal2)[(rel * 2 + h) * 256 + k] = s;
    } else if (bx < 14) {
        int t = (bx - 12) * 256 + tid;
        if (t < 256) {
            p.bc1[t] = 0.5f * (bf2f(p.b1[0][t]) + bf2f(p.b1[0][256 + t]) +
                               bf2f(p.b1[1][t]) + bf2f(p.b1[1][256 + t]));
        } else if (t < 384) {
            int o = t - 256;
            p.bc2[o] = 0.5f * (bf2f(p.b2[0][o]) + bf2f(p.b2[0][128 + o]) +
                               bf2f(p.b2[1][o]) + bf2f(p.b2[1][128 + o]));
        }
    } else if (bx < 78) {               // Wc1f repack: K=512, M=256, KS=16
        int i = (bx - 14) * 256 + tid;  // [0, 16384)
        int lane = i & 63;
        int t2 = i >> 6;
        int ct = t2 >> 4, ks = t2 & 15;
        int col = ct * 16 + (lane & 15);
        bf16_t* out = p.Wc1f + (size_t)i * 8;
#pragma unroll
        for (int j = 0; j < 8; ++j) {
            int r = ks * 32 + ((lane >> 4) << 3) + j;   // [0,512)
            int rel = r >> 8, h = (r >> 7) & 1, kx = r & 127;
            out[j] = f2bf(0.5f * bf2f(p.W1[rel][kx * 512 + h * 256 + col]));
        }
    } else {                            // Wc2f repack: K=1024, M=128, KS=32
        int i = (bx - 78) * 256 + tid;  // [0, 16384)
        int lane = i & 63;
        int t2 = i >> 6;
        int ct = t2 >> 5, ks = t2 & 31;
        int col = ct * 16 + (lane & 15);
        bf16_t* out = p.Wc2f + (size_t)i * 8;
#pragma unroll
        for (int j = 0; j < 8; ++j) {
            int r = ks * 32 + ((lane >> 4) << 3) + j;   // [0,1024)
            int rel = r >> 9, h = (r >> 8) & 1, kx = r & 255;
            out[j] = f2bf(0.5f * bf2f(p.W2[rel][kx * 256 + h * 128 + col]));
        }
    }
}

// ---------------- CSR build ----------------
struct Csr2 {
    const int* src[2];
    const int* dst[2];
    int* cnt[2];
    int* offs[2];
    int* cursor[2];
    int* srcc[2];
};
// merged: prep (142 blocks) + hist (2x1250 blocks)
struct PhArgs { PrepArgs p; Csr2 c; };
__global__ void prep_hist_kernel(PhArgs a) {
    int bx = blockIdx.x;
    if (bx < 142) {
        prep_body(a.p, bx, threadIdx.x);
    } else {
        int b = bx - 142;
        int rel = b / 1250;
        int i = (b - rel * 1250) * 256 + threadIdx.x;
        if (i < NE) atomicAdd(&a.c.cnt[rel][a.c.dst[rel][i]], 1);
    }
}

__global__ void scan2_kernel(Csr2 c, int n) {
    int rel = blockIdx.x;
    const int* cnt = c.cnt[rel];
    int* offs = c.offs[rel];
    int* cursor = c.cursor[rel];
    __shared__ int sums[256];
    int t = threadIdx.x;
    int chunk = (n + 255) >> 8;
    int lo = t * chunk;
    int hi = min(lo + chunk, n);
    int s = 0;
    for (int i = lo; i < hi; ++i) s += cnt[i];
    sums[t] = s;
    __syncthreads();
    if (t == 0) {
        int run = 0;
        for (int i = 0; i < 256; ++i) { int v = sums[i]; sums[i] = run; run += v; }
    }
    __syncthreads();
    int run = sums[t];
    for (int i = lo; i < hi; ++i) { int v = cnt[i]; offs[i] = run; cursor[i] = run; run += v; }
    if (t == 255) offs[n] = run;
}

// merged: elr1 (5000 blocks) + scatter (2x1250 blocks)
__global__ void scat_elr_kernel(Csr2 c, const bf16_t* __restrict__ x,
                                const float* __restrict__ wal1,
                                const float* __restrict__ war1,
                                float* __restrict__ el0, float* __restrict__ er0,
                                float* __restrict__ el1, float* __restrict__ er1) {
    __shared__ float wl[512], wr[512];
    int t = threadIdx.x;
    if (blockIdx.x < 5000) {
        wl[t] = wal1[t]; wl[t + 256] = wal1[t + 256];
        wr[t] = war1[t]; wr[t + 256] = war1[t + 256];
        __syncthreads();
        int w = t >> 6, lane = t & 63;
        int node = blockIdx.x * 4 + w;
        unsigned pk = ((const unsigned*)x)[node * 64 + lane];
        float v0 = bf2f((bf16_t)(pk & 0xffffu));
        float v1 = bf2f((bf16_t)(pk >> 16));
        float de[4], dr[4];
#pragma unroll
        for (int cch = 0; cch < 4; ++cch) {
            de[cch] = v0 * wl[cch * 128 + 2 * lane] + v1 * wl[cch * 128 + 2 * lane + 1];
            dr[cch] = v0 * wr[cch * 128 + 2 * lane] + v1 * wr[cch * 128 + 2 * lane + 1];
        }
#pragma unroll
        for (int off = 32; off > 0; off >>= 1) {
#pragma unroll
            for (int cch = 0; cch < 4; ++cch) {
                de[cch] += __shfl_xor(de[cch], off);
                dr[cch] += __shfl_xor(dr[cch], off);
            }
        }
        if (lane == 0) {
            el0[node * 2 + 0] = de[0]; el0[node * 2 + 1] = de[1];
            el1[node * 2 + 0] = de[2]; el1[node * 2 + 1] = de[3];
            er0[node * 2 + 0] = dr[0]; er0[node * 2 + 1] = dr[1];
            er1[node * 2 + 0] = dr[2]; er1[node * 2 + 1] = dr[3];
        }
    } else {
        int b = blockIdx.x - 5000;
        int rel = b / 1250;
        int i = (b - rel * 1250) * 256 + t;
        if (i < NE) {
            int p = atomicAdd(&c.cursor[rel][c.dst[rel][i]], 1);
            c.srcc[rel][p] = c.src[rel][i];
        }
    }
}

// ---------------- agg: ONE WAVE PER DST, register softmax ----------------
// Row has 128*VD dims (bf16); lane holds dword indices lane*VD..lane*VD+VD-1
// (dims 2w,2w+1 per dword). y row = 4 segments (rel,h) of 64*VD dwords each,
// K-order matching Wc repack: K = rel*(256*VD) + h*(128*VD) + dim.
// Softmax: lane j owns edge j (chunked by 64); butterfly -> (m,s); alpha kept
// in lane registers; gather broadcasts (src,a0,a1) via uniform __shfl.
template <int VD>
__global__ void agg_wave_kernel(
    const int* __restrict__ offs0, const int* __restrict__ srcc0,
    const float* __restrict__ el0, const float* __restrict__ er0,
    const int* __restrict__ offs1, const int* __restrict__ srcc1,
    const float* __restrict__ el1, const float* __restrict__ er1,
    const unsigned* __restrict__ rows, bf16_t* __restrict__ y) {
    int wv = threadIdx.x >> 6, lane = threadIdx.x & 63;
    int d = blockIdx.x * 4 + wv;
    float acc[2][2][2 * VD];
#pragma unroll
    for (int r = 0; r < 2; ++r)
#pragma unroll
        for (int h = 0; h < 2; ++h)
#pragma unroll
            for (int k = 0; k < 2 * VD; ++k) acc[r][h][k] = 0.f;

#pragma unroll 1
    for (int rel = 0; rel < 2; ++rel) {
        const int* offs = rel ? offs1 : offs0;
        const int* srcc = rel ? srcc1 : srcc0;
        const float* el = rel ? el1 : el0;
        const float* er = rel ? er1 : er0;
        int beg = offs[d];
        int deg = offs[d + 1] - beg;
        if (deg == 0) continue;
        float erh0 = er[d * 2], erh1 = er[d * 2 + 1];

        // ---- stats ----
        float m0 = -1e30f, s0 = 0.f, m1 = -1e30f, s1 = 0.f;
        float e0r = -1e30f, e1r = -1e30f;
        int sr = 0;
#pragma unroll 1
        for (int cc = 0; cc < deg; cc += 64) {
            int j = cc + lane;
            float e0 = -1e30f, e1 = -1e30f;
            int s = 0;
            if (j < deg) {
                s = srcc[beg + j];
                float2 ev = ((const float2*)el)[s];
                e0 = lrelu(ev.x + erh0);
                e1 = lrelu(ev.y + erh1);
            }
            if (cc == 0) { e0r = e0; e1r = e1; sr = s; }
            float cm0 = e0, cm1 = e1;
#pragma unroll
            for (int off = 32; off > 0; off >>= 1) {
                cm0 = fmaxf(cm0, __shfl_xor(cm0, off));
                cm1 = fmaxf(cm1, __shfl_xor(cm1, off));
            }
            float p0 = __expf(e0 - cm0);
            float p1 = __expf(e1 - cm1);
#pragma unroll
            for (int off = 32; off > 0; off >>= 1) {
                p0 += __shfl_xor(p0, off);
                p1 += __shfl_xor(p1, off);
            }
            float nm0 = fmaxf(m0, cm0);
            s0 = s0 * __expf(m0 - nm0) + p0 * __expf(cm0 - nm0);
            m0 = nm0;
            float nm1 = fmaxf(m1, cm1);
            s1 = s1 * __expf(m1 - nm1) + p1 * __expf(cm1 - nm1);
            m1 = nm1;
        }
        float i0 = 1.f / fmaxf(s0, 1e-9f);
        float i1 = 1.f / fmaxf(s1, 1e-9f);

        // ---- gather ----
#pragma unroll 1
        for (int cc = 0; cc < deg; cc += 64) {
            float a0 = 0.f, a1 = 0.f;
            int s = 0;
            if (cc == 0 && deg <= 64) {
                s = sr;
                a0 = __expf(e0r - m0) * i0;   // lanes >= deg: e0r=-1e30 -> 0
                a1 = __expf(e1r - m1) * i1;
            } else {
                int j = cc + lane;
                if (j < deg) {
                    s = srcc[beg + j];
                    float2 ev = ((const float2*)el)[s];
                    a0 = __expf(lrelu(ev.x + erh0) - m0) * i0;
                    a1 = __expf(lrelu(ev.y + erh1) - m1) * i1;
                }
            }
            int lim = min(64, deg - cc);
#pragma unroll 4
            for (int j = 0; j < lim; ++j) {
                int sj = __shfl(s, j);
                float p0 = __shfl(a0, j);
                float p1 = __shfl(a1, j);
                const unsigned* p = rows + (size_t)sj * (64 * VD) + lane * VD;
                if constexpr (VD == 1) {
                    unsigned pk = *p;
                    float v0 = bf2f((bf16_t)(pk & 0xffffu));
                    float v1 = bf2f((bf16_t)(pk >> 16));
                    acc[rel][0][0] += p0 * v0; acc[rel][0][1] += p0 * v1;
                    acc[rel][1][0] += p1 * v0; acc[rel][1][1] += p1 * v1;
                } else {
                    uint2 pk = *(const uint2*)p;
                    float v0 = bf2f((bf16_t)(pk.x & 0xffffu));
                    float v1 = bf2f((bf16_t)(pk.x >> 16));
                    float v2 = bf2f((bf16_t)(pk.y & 0xffffu));
                    float v3 = bf2f((bf16_t)(pk.y >> 16));
                    acc[rel][0][0] += p0 * v0; acc[rel][0][1] += p0 * v1;
                    acc[rel][0][2] += p0 * v2; acc[rel][0][3] += p0 * v3;
                    acc[rel][1][0] += p1 * v0; acc[rel][1][1] += p1 * v1;
                    acc[rel][1][2] += p1 * v2; acc[rel][1][3] += p1 * v3;
                }
            }
        }
    }

    // ---- store y row ----
    unsigned* yp = (unsigned*)y + (size_t)d * (4 * 64 * VD);
#pragma unroll
    for (int rel = 0; rel < 2; ++rel)
#pragma unroll
        for (int h = 0; h < 2; ++h) {
            unsigned* seg = yp + ((rel * 2 + h) * 64 + lane) * VD;
            if constexpr (VD == 1) {
                seg[0] = (unsigned)f2bf(acc[rel][h][0]) |
                         ((unsigned)f2bf(acc[rel][h][1]) << 16);
            } else {
                uint2 o;
                o.x = (unsigned)f2bf(acc[rel][h][0]) |
                      ((unsigned)f2bf(acc[rel][h][1]) << 16);
                o.y = (unsigned)f2bf(acc[rel][h][2]) |
                      ((unsigned)f2bf(acc[rel][h][3]) << 16);
                *(uint2*)seg = o;
            }
        }
}

// -------- gemm1: h1 = relu(y1 @ Wc1 + bc1); epilogue: el2/er2 atomics --------
__global__ void gemm1_kernel(const bf16_t* __restrict__ A, const bf16_t* __restrict__ Wf,
                             const float* __restrict__ bc1, bf16_t* __restrict__ h1,
                             const float* __restrict__ wal2, const float* __restrict__ war2,
                             float* __restrict__ el2_0, float* __restrict__ er2_0,
                             float* __restrict__ el2_1, float* __restrict__ er2_1,
                             int n) {
    constexpr int K = 512, M = 256, KS = 16;
    int w = threadIdx.x >> 6, lane = threadIdx.x & 63;
    int q = lane >> 4, m16 = lane & 15;
    int rf = blockIdx.y * 64 + w * 16;
    if (rf >= n) return;
    f32x4 acc[4] = {};
    const bf16_t* Arow = A + (size_t)(rf + m16) * K + q * 8;
    for (int ks = 0; ks < KS; ++ks) {
        short8 af = *(const short8*)(Arow + ks * 32);
#pragma unroll
        for (int f = 0; f < 4; ++f) {
            int ct = blockIdx.x * 4 + f;
            short8 bfr = *(const short8*)(Wf + ((size_t)(ct * KS + ks) * 64 + lane) * 8);
            acc[f] = __builtin_amdgcn_mfma_f32_16x16x32_bf16(af, bfr, acc[f], 0, 0, 0);
        }
    }
    int col0 = blockIdx.x * 64;
    float del[2][2][4] = {};
    float der[2][2][4] = {};
#pragma unroll
    for (int f = 0; f < 4; ++f) {
        int col = col0 + f * 16 + m16;
        float bcv = bc1[col];
        float wle[2][2], wre[2][2];
#pragma unroll
        for (int rel = 0; rel < 2; ++rel)
#pragma unroll
            for (int h = 0; h < 2; ++h) {
                wle[rel][h] = wal2[(rel * 2 + h) * 256 + col];
                wre[rel][h] = war2[(rel * 2 + h) * 256 + col];
            }
#pragma unroll
        for (int r = 0; r < 4; ++r) {
            int row = rf + q * 4 + r;
            float v = fmaxf(acc[f][r] + bcv, 0.f);
            bf16_t hb = f2bf(v);
            h1[(size_t)row * M + col] = hb;
            float vb = bf2f(hb);
#pragma unroll
            for (int rel = 0; rel < 2; ++rel)
#pragma unroll
                for (int h = 0; h < 2; ++h) {
                    del[rel][h][r] += vb * wle[rel][h];
                    der[rel][h][r] += vb * wre[rel][h];
                }
        }
    }
#pragma unroll
    for (int off = 1; off < 16; off <<= 1) {
#pragma unroll
        for (int rel = 0; rel < 2; ++rel)
#pragma unroll
            for (int h = 0; h < 2; ++h)
#pragma unroll
                for (int r = 0; r < 4; ++r) {
                    del[rel][h][r] += __shfl_xor(del[rel][h][r], off);
                    der[rel][h][r] += __shfl_xor(der[rel][h][r], off);
                }
    }
    if (m16 == 0) {
#pragma unroll
        for (int r = 0; r < 4; ++r) {
            int row = rf + q * 4 + r;
            atomicAdd(&el2_0[row * 2 + 0], del[0][0][r]);
            atomicAdd(&el2_0[row * 2 + 1], del[0][1][r]);
            atomicAdd(&el2_1[row * 2 + 0], del[1][0][r]);
            atomicAdd(&el2_1[row * 2 + 1], del[1][1][r]);
            atomicAdd(&er2_0[row * 2 + 0], der[0][0][r]);
            atomicAdd(&er2_0[row * 2 + 1], der[0][1][r]);
            atomicAdd(&er2_1[row * 2 + 0], der[1][0][r]);
            atomicAdd(&er2_1[row * 2 + 1], der[1][1][r]);
        }
    }
}

// -------- gemm2: out = y2 @ Wc2 + bc2 (final store, flag dtype) --------
__global__ void gemm2_kernel(const bf16_t* __restrict__ A, const bf16_t* __restrict__ Wf,
                             const float* __restrict__ bc2, void* __restrict__ out,
                             const int* __restrict__ flag, int n) {
    constexpr int K = 1024, M = 128, KS = 32;
    int w = threadIdx.x >> 6, lane = threadIdx.x & 63;
    int q = lane >> 4, m16 = lane & 15;
    int rf = blockIdx.y * 64 + w * 16;
    if (rf >= n) return;
    f32x4 acc[4] = {};
    const bf16_t* Arow = A + (size_t)(rf + m16) * K + q * 8;
    for (int ks = 0; ks < KS; ++ks) {
        short8 af = *(const short8*)(Arow + ks * 32);
#pragma unroll
        for (int f = 0; f < 4; ++f) {
            int ct = blockIdx.x * 4 + f;
            short8 bfr = *(const short8*)(Wf + ((size_t)(ct * KS + ks) * 64 + lane) * 8);
            acc[f] = __builtin_amdgcn_mfma_f32_16x16x32_bf16(af, bfr, acc[f], 0, 0, 0);
        }
    }
    int col0 = blockIdx.x * 64;
    int fl = *flag;
#pragma unroll
    for (int f = 0; f < 4; ++f) {
        int col = col0 + f * 16 + m16;
        float bcv = bc2[col];
#pragma unroll
        for (int r = 0; r < 4; ++r) {
            int row = rf + q * 4 + r;
            float v = acc[f][r] + bcv;
            if (fl) ((float*)out)[(size_t)row * M + col] = v;
            else    ((bf16_t*)out)[(size_t)row * M + col] = f2bf(v);
        }
    }
}

extern "C" void kernel_launch(void* const* d_in, const int* in_sizes, int n_in,
                              void* d_out, int out_size, void* d_ws, size_t ws_size,
                              hipStream_t stream) {
    (void)in_sizes; (void)n_in; (void)out_size; (void)ws_size;
    const int* src0 = (const int*)d_in[1];
    const int* dst0 = (const int*)d_in[2];
    const int* src1 = (const int*)d_in[3];
    const int* dst1 = (const int*)d_in[4];

    char* ws = (char*)d_ws;
    size_t off = 0;
    auto alloc = [&](size_t bytes) -> void* {
        void* p = ws + off;
        off = (off + bytes + 255) & ~(size_t)255;
        return p;
    };
    int* flag = (int*)alloc(4);
    static const int tn[NT] = {NN * 128,
                               128 * 512, 512, 512, 512,
                               128 * 512, 512, 512, 512,
                               256 * 256, 256, 256, 256,
                               256 * 256, 256, 256, 256};
    bf16_t* tb[NT];
    for (int i = 0; i < NT; ++i) tb[i] = (bf16_t*)alloc((size_t)tn[i] * 2);
    bf16_t* xb = tb[0];

    bf16_t* Wc1f = (bf16_t*)alloc((size_t)512 * 256 * 2);
    bf16_t* Wc2f = (bf16_t*)alloc((size_t)1024 * 128 * 2);
    float* wal1 = (float*)alloc(512 * 4);
    float* war1 = (float*)alloc(512 * 4);
    float* wal2 = (float*)alloc(1024 * 4);
    float* war2 = (float*)alloc(1024 * 4);
    float* bc1  = (float*)alloc(256 * 4);
    float* bc2  = (float*)alloc(128 * 4);

    // zero region: cnt0, cnt1, el2/er2 (atomic targets)
    char* zbeg = ws + off;
    int* cnt0 = (int*)alloc(NN * 4);
    int* cnt1 = (int*)alloc(NN * 4);
    float* el2_0 = (float*)alloc(NN * 2 * 4);
    float* er2_0 = (float*)alloc(NN * 2 * 4);
    float* el2_1 = (float*)alloc(NN * 2 * 4);
    float* er2_1 = (float*)alloc(NN * 2 * 4);
    char* zend = ws + off;
    int zcount = (int)((zend - zbeg) >> 2);

    int* offs0 = (int*)alloc((NN + 1) * 4);
    int* offs1 = (int*)alloc((NN + 1) * 4);
    int* cur0  = (int*)alloc(NN * 4);
    int* cur1  = (int*)alloc(NN * 4);
    int* srcc0 = (int*)alloc(NE * 4);
    int* srcc1 = (int*)alloc(NE * 4);
    float* el1_0 = (float*)alloc(NN * 2 * 4);
    float* er1_0 = (float*)alloc(NN * 2 * 4);
    float* el1_1 = (float*)alloc(NN * 2 * 4);
    float* er1_1 = (float*)alloc(NN * 2 * 4);
    bf16_t* h1 = (bf16_t*)alloc((size_t)NN * 256 * 2);
    bf16_t* Y  = (bf16_t*)alloc((size_t)NN * 1024 * 2);   // y1 [N,512] then y2 [N,1024]
    bf16_t* y1 = Y;
    bf16_t* y2 = Y;

    // ---- 1. convert + zero + inline dtype detect ----
    CzArgs cz;
    static const int din_idx[NT] = {0, 5, 6, 7, 8, 9, 10, 11, 12,
                                    13, 14, 15, 16, 17, 18, 19, 20};
    int total_blocks = 0;
    for (int i = 0; i < NT; ++i) {
        cz.src[i] = d_in[din_idx[i]];
        cz.dst[i] = tb[i];
        cz.n[i] = tn[i];
        cz.nblk[i] = (tn[i] + 255) / 256;
        total_blocks += cz.nblk[i];
    }
    cz.zero_ptr = (int*)zbeg;
    cz.zn = zcount;
    cz.nblk[NT] = (zcount + 255) / 256;
    total_blocks += cz.nblk[NT];
    cz.xsrc = (const unsigned*)d_in[0];
    cz.flag_out = flag;
    convzero_kernel<<<total_blocks, 256, 0, stream>>>(cz);

    // ---- 2. prep + hist ----
    PhArgs ph;
    ph.p.W1[0] = tb[1];  ph.p.W1[1] = tb[5];
    ph.p.W2[0] = tb[9];  ph.p.W2[1] = tb[13];
    ph.p.al1[0] = tb[2]; ph.p.ar1[0] = tb[3];
    ph.p.al1[1] = tb[6]; ph.p.ar1[1] = tb[7];
    ph.p.al2[0] = tb[10]; ph.p.ar2[0] = tb[11];
    ph.p.al2[1] = tb[14]; ph.p.ar2[1] = tb[15];
    ph.p.b1[0] = tb[4];  ph.p.b1[1] = tb[8];
    ph.p.b2[0] = tb[12]; ph.p.b2[1] = tb[16];
    ph.p.wal1 = wal1; ph.p.war1 = war1;
    ph.p.wal2 = wal2; ph.p.war2 = war2;
    ph.p.bc1 = bc1; ph.p.bc2 = bc2;
    ph.p.Wc1f = Wc1f; ph.p.Wc2f = Wc2f;
    ph.c.src[0] = src0; ph.c.src[1] = src1;
    ph.c.dst[0] = dst0; ph.c.dst[1] = dst1;
    ph.c.cnt[0] = cnt0; ph.c.cnt[1] = cnt1;
    ph.c.offs[0] = offs0; ph.c.offs[1] = offs1;
    ph.c.cursor[0] = cur0; ph.c.cursor[1] = cur1;
    ph.c.srcc[0] = srcc0; ph.c.srcc[1] = srcc1;
    prep_hist_kernel<<<142 + 2500, 256, 0, stream>>>(ph);

    // ---- 3. scan ----
    scan2_kernel<<<2, 256, 0, stream>>>(ph.c, NN);

    // ---- 4. scatter + elr1 ----
    scat_elr_kernel<<<5000 + 2500, 256, 0, stream>>>(
        ph.c, xb, wal1, war1, el1_0, er1_0, el1_1, er1_1);

    // ---- 5. agg1: gather x rows -> y1[N,512] ----
    agg_wave_kernel<1><<<NN / 4, 256, 0, stream>>>(
        offs0, srcc0, el1_0, er1_0, offs1, srcc1, el1_1, er1_1,
        (const unsigned*)xb, y1);

    // ---- 6. gemm1 -> h1, el2/er2 ----
    gemm1_kernel<<<dim3(4, 313), 256, 0, stream>>>(
        y1, Wc1f, bc1, h1, wal2, war2, el2_0, er2_0, el2_1, er2_1, NN);

    // ---- 7. agg2: gather h1 rows -> y2[N,1024] ----
    agg_wave_kernel<2><<<NN / 4, 256, 0, stream>>>(
        offs0, srcc0, el2_0, er2_0, offs1, srcc1, el2_1, er2_1,
        (const unsigned*)h1, y2);

    // ---- 8. gemm2 -> out ----
    gemm2_kernel<<<dim3(2, 313), 256, 0, stream>>>(y2, Wc2f, bc2, d_out, flag, NN);
}

// Round 8
// 445.698 us; speedup vs baseline: 1.3646x; 1.3646x over previous
//
#include <hip/hip_runtime.h>

// RGAT: 2-layer, 2-relation GAT. N=20000, E=320000/rel, D=128, H=2.
// Round 8: revert agg to round-6 proven 4-wave/LDS-merge kernels (round-7's
// one-wave-per-dst hit a 64KB compiler LDS-scratch occupancy trap); keep
// round-7 merged pre-pipeline (8 dispatches); CAP 192->64 to shrink agg LDS.

#define NN 20000
#define NE 320000

typedef unsigned short bf16_t;
typedef __attribute__((ext_vector_type(8))) short short8;
typedef __attribute__((ext_vector_type(4))) float f32x4;

__device__ __forceinline__ float bf2f(bf16_t u) {
    return __uint_as_float(((unsigned)u) << 16);
}
__device__ __forceinline__ bf16_t f2bf(float f) {
    unsigned x = __float_as_uint(f);
    unsigned r = (x + 0x7fffu + ((x >> 16) & 1u)) >> 16;   // RNE
    return (bf16_t)r;
}
__device__ __forceinline__ float lrelu(float v) {
    return (v > 0.f) ? v : 0.2f * v;
}

// ------------- convert 17 float tensors to bf16 + zero region ---------------
#define NT 17
struct CzArgs {
    const void* src[NT];
    bf16_t* dst[NT];
    int n[NT];
    int nblk[NT + 1];
    int* zero_ptr;
    int zn;
    const unsigned* xsrc;
    int* flag_out;
};
__global__ void convzero_kernel(CzArgs a) {
    __shared__ int fl_s;
    int t = threadIdx.x;
    if (t < 64) {
        float mx = 0.f;
        for (int i = t; i < 256; i += 64) {
            float v = fabsf(bf2f((bf16_t)(a.xsrc[i] & 0xffffu)));
            v = (v <= 1e30f) ? v : 1e30f;
            mx = fmaxf(mx, v);
        }
        for (int off = 32; off > 0; off >>= 1) mx = fmaxf(mx, __shfl_xor(mx, off));
        if (t == 0) {
            int f = (mx > 1e6f) ? 1 : 0;
            fl_s = f;
            if (blockIdx.x == 0) *a.flag_out = f;
        }
    }
    __syncthreads();
    int flag = fl_s;
    int b = blockIdx.x;
    int ti = 0;
#pragma unroll 1
    for (; ti <= NT; ++ti) {
        if (b < a.nblk[ti]) break;
        b -= a.nblk[ti];
    }
    int i = b * 256 + t;
    if (ti < NT) {
        if (i < a.n[ti]) {
            if (flag) a.dst[ti][i] = f2bf(((const float*)a.src[ti])[i]);
            else      a.dst[ti][i] = ((const bf16_t*)a.src[ti])[i];
        }
    } else {
        if (i < a.zn) a.zero_ptr[i] = 0;
    }
}

// ---------------- prep: wal/war vectors, combined biases, Wc frag repack ----
struct PrepArgs {
    const bf16_t *W1[2], *W2[2];
    const bf16_t *al1[2], *ar1[2], *al2[2], *ar2[2];
    const bf16_t *b1[2], *b2[2];
    float *wal1, *war1;     // [2rel*2h*128]
    float *wal2, *war2;     // [2rel*2h*256]
    float *bc1, *bc2;       // [256], [128]
    bf16_t *Wc1f, *Wc2f;
};
__device__ __forceinline__ void prep_body(const PrepArgs& p, int bx, int tid) {
    if (bx < 4) {
        int t = bx * 256 + tid;
        int lr = t >> 9, rel = (t >> 8) & 1, h = (t >> 7) & 1, k = t & 127;
        const bf16_t* av = lr ? p.ar1[rel] : p.al1[rel];
        const bf16_t* W = p.W1[rel];
        float s = 0.f;
        for (int o = 0; o < 256; ++o)
            s += bf2f(W[k * 512 + h * 256 + o]) * bf2f(av[h * 256 + o]);
        (lr ? p.war1 : p.wal1)[(rel * 2 + h) * 128 + k] = s;
    } else if (bx < 12) {
        int t = (bx - 4) * 256 + tid;
        int lr = t >> 10, rel = (t >> 9) & 1, h = (t >> 8) & 1, k = t & 255;
        const bf16_t* av = lr ? p.ar2[rel] : p.al2[rel];
        const bf16_t* W = p.W2[rel];
        float s = 0.f;
        for (int o = 0; o < 128; ++o)
            s += bf2f(W[k * 256 + h * 128 + o]) * bf2f(av[h * 128 + o]);
        (lr ? p.war2 : p.wal2)[(rel * 2 + h) * 256 + k] = s;
    } else if (bx < 14) {
        int t = (bx - 12) * 256 + tid;
        if (t < 256) {
            p.bc1[t] = 0.5f * (bf2f(p.b1[0][t]) + bf2f(p.b1[0][256 + t]) +
                               bf2f(p.b1[1][t]) + bf2f(p.b1[1][256 + t]));
        } else if (t < 384) {
            int o = t - 256;
            p.bc2[o] = 0.5f * (bf2f(p.b2[0][o]) + bf2f(p.b2[0][128 + o]) +
                               bf2f(p.b2[1][o]) + bf2f(p.b2[1][128 + o]));
        }
    } else if (bx < 78) {               // Wc1f: K=512, M=256, KS=16
        int i = (bx - 14) * 256 + tid;
        int lane = i & 63;
        int t2 = i >> 6;
        int ct = t2 >> 4, ks = t2 & 15;
        int col = ct * 16 + (lane & 15);
        bf16_t* out = p.Wc1f + (size_t)i * 8;
#pragma unroll
        for (int j = 0; j < 8; ++j) {
            int r = ks * 32 + ((lane >> 4) << 3) + j;
            int rel = r >> 8, h = (r >> 7) & 1, kx = r & 127;
            out[j] = f2bf(0.5f * bf2f(p.W1[rel][kx * 512 + h * 256 + col]));
        }
    } else {                            // Wc2f: K=1024, M=128, KS=32
        int i = (bx - 78) * 256 + tid;
        int lane = i & 63;
        int t2 = i >> 6;
        int ct = t2 >> 5, ks = t2 & 31;
        int col = ct * 16 + (lane & 15);
        bf16_t* out = p.Wc2f + (size_t)i * 8;
#pragma unroll
        for (int j = 0; j < 8; ++j) {
            int r = ks * 32 + ((lane >> 4) << 3) + j;
            int rel = r >> 9, h = (r >> 8) & 1, kx = r & 255;
            out[j] = f2bf(0.5f * bf2f(p.W2[rel][kx * 256 + h * 128 + col]));
        }
    }
}

// ---------------- CSR build ----------------
struct Csr2 {
    const int* src[2];
    const int* dst[2];
    int* cnt[2];
    int* offs[2];
    int* cursor[2];
    int* srcc[2];
};
struct PhArgs { PrepArgs p; Csr2 c; };
__global__ void prep_hist_kernel(PhArgs a) {
    int bx = blockIdx.x;
    if (bx < 142) {
        prep_body(a.p, bx, threadIdx.x);
    } else {
        int b = bx - 142;
        int rel = b / 1250;
        int i = (b - rel * 1250) * 256 + threadIdx.x;
        if (i < NE) atomicAdd(&a.c.cnt[rel][a.c.dst[rel][i]], 1);
    }
}

__global__ void scan2_kernel(Csr2 c, int n) {
    int rel = blockIdx.x;
    const int* cnt = c.cnt[rel];
    int* offs = c.offs[rel];
    int* cursor = c.cursor[rel];
    __shared__ int sums[256];
    int t = threadIdx.x;
    int chunk = (n + 255) >> 8;
    int lo = t * chunk;
    int hi = min(lo + chunk, n);
    int s = 0;
    for (int i = lo; i < hi; ++i) s += cnt[i];
    sums[t] = s;
    __syncthreads();
    if (t == 0) {
        int run = 0;
        for (int i = 0; i < 256; ++i) { int v = sums[i]; sums[i] = run; run += v; }
    }
    __syncthreads();
    int run = sums[t];
    for (int i = lo; i < hi; ++i) { int v = cnt[i]; offs[i] = run; cursor[i] = run; run += v; }
    if (t == 255) offs[n] = run;
}

__global__ void scat_elr_kernel(Csr2 c, const bf16_t* __restrict__ x,
                                const float* __restrict__ wal1,
                                const float* __restrict__ war1,
                                float* __restrict__ el0, float* __restrict__ er0,
                                float* __restrict__ el1, float* __restrict__ er1) {
    __shared__ float wl[512], wr[512];
    int t = threadIdx.x;
    if (blockIdx.x < 5000) {
        wl[t] = wal1[t]; wl[t + 256] = wal1[t + 256];
        wr[t] = war1[t]; wr[t + 256] = war1[t + 256];
        __syncthreads();
        int w = t >> 6, lane = t & 63;
        int node = blockIdx.x * 4 + w;
        unsigned pk = ((const unsigned*)x)[node * 64 + lane];
        float v0 = bf2f((bf16_t)(pk & 0xffffu));
        float v1 = bf2f((bf16_t)(pk >> 16));
        float de[4], dr[4];
#pragma unroll
        for (int cch = 0; cch < 4; ++cch) {
            de[cch] = v0 * wl[cch * 128 + 2 * lane] + v1 * wl[cch * 128 + 2 * lane + 1];
            dr[cch] = v0 * wr[cch * 128 + 2 * lane] + v1 * wr[cch * 128 + 2 * lane + 1];
        }
#pragma unroll
        for (int off = 32; off > 0; off >>= 1) {
#pragma unroll
            for (int cch = 0; cch < 4; ++cch) {
                de[cch] += __shfl_xor(de[cch], off);
                dr[cch] += __shfl_xor(dr[cch], off);
            }
        }
        if (lane == 0) {
            el0[node * 2 + 0] = de[0]; el0[node * 2 + 1] = de[1];
            el1[node * 2 + 0] = de[2]; el1[node * 2 + 1] = de[3];
            er0[node * 2 + 0] = dr[0]; er0[node * 2 + 1] = dr[1];
            er1[node * 2 + 0] = dr[2]; er1[node * 2 + 1] = dr[3];
        }
    } else {
        int b = blockIdx.x - 5000;
        int rel = b / 1250;
        int i = (b - rel * 1250) * 256 + t;
        if (i < NE) {
            int p = atomicAdd(&c.cursor[rel][c.dst[rel][i]], 1);
            c.srcc[rel][p] = c.src[rel][i];
        }
    }
}

// ---------------- agg1: softmax + gather x rows -> y1[N,512] ----------------
// (round-6 proven kernel; CAP 192->64, LDS ~9.6 KB)
__global__ void agg1_kernel(
    const int* __restrict__ offs0, const int* __restrict__ srcc0,
    const float* __restrict__ el0, const float* __restrict__ er0,
    const int* __restrict__ offs1, const int* __restrict__ srcc1,
    const float* __restrict__ el1, const float* __restrict__ er1,
    const bf16_t* __restrict__ x, bf16_t* __restrict__ y1) {
    constexpr int CAP = 64;
    __shared__ float sh[4][512];
    __shared__ int   ss[2][CAP];
    __shared__ float se[2][2 * CAP];
    __shared__ float fin_m[4], fin_inv[4];
    int d = blockIdx.x;
    int t = threadIdx.x;
    int w = t >> 6, lane = t & 63;
    int beg0 = offs0[d], deg0 = offs0[d + 1] - beg0;
    int beg1 = offs1[d], deg1 = offs1[d + 1] - beg1;
    int c0 = min(deg0, CAP), c1 = min(deg1, CAP);
    float er00 = er0[d * 2], er01 = er0[d * 2 + 1];
    float er10 = er1[d * 2], er11 = er1[d * 2 + 1];

    for (int j = t; j < c0; j += 256) {
        int s = srcc0[beg0 + j];
        ss[0][j] = s;
        float2 ev = ((const float2*)el0)[s];
        se[0][2 * j] = lrelu(ev.x + er00);
        se[0][2 * j + 1] = lrelu(ev.y + er01);
    }
    for (int j = t; j < c1; j += 256) {
        int s = srcc1[beg1 + j];
        ss[1][j] = s;
        float2 ev = ((const float2*)el1)[s];
        se[1][2 * j] = lrelu(ev.x + er10);
        se[1][2 * j + 1] = lrelu(ev.y + er11);
    }
    __syncthreads();
    if (w < 2) {
        int rel = w;
        int head = lane & 1;
        int cc = rel ? c1 : c0;
        int deg = rel ? deg1 : deg0;
        int beg = rel ? beg1 : beg0;
        const int* sc = rel ? srcc1 : srcc0;
        const float* elp = rel ? el1 : el0;
        float erh = rel ? (head ? er11 : er10) : (head ? er01 : er00);
        float m = -1e30f, s = 0.f;
        for (int j = lane >> 1; j < cc; j += 32) {
            float e = se[rel][2 * j + head];
            float mn = fmaxf(m, e);
            s = s * __expf(m - mn) + __expf(e - mn);
            m = mn;
        }
        for (int j = cc + (lane >> 1); j < deg; j += 32) {
            int sv = sc[beg + j];
            float e = lrelu(elp[sv * 2 + head] + erh);
            float mn = fmaxf(m, e);
            s = s * __expf(m - mn) + __expf(e - mn);
            m = mn;
        }
#pragma unroll
        for (int off = 2; off < 64; off <<= 1) {
            float om = __shfl_xor(m, off);
            float os = __shfl_xor(s, off);
            float mn = fmaxf(m, om);
            s = s * __expf(m - mn) + os * __expf(om - mn);
            m = mn;
        }
        if (lane < 2) {
            fin_m[rel * 2 + head] = m;
            fin_inv[rel * 2 + head] = 1.f / fmaxf(s, 1e-9f);
        }
    }
    __syncthreads();
    for (int i = t; i < 2 * c0; i += 256)
        se[0][i] = __expf(se[0][i] - fin_m[i & 1]) * fin_inv[i & 1];
    for (int i = t; i < 2 * c1; i += 256)
        se[1][i] = __expf(se[1][i] - fin_m[2 + (i & 1)]) * fin_inv[2 + (i & 1)];
    __syncthreads();

    const unsigned* xp = (const unsigned*)x;
    float a00 = 0.f, a01 = 0.f, a10 = 0.f, a11 = 0.f;
    float b00 = 0.f, b01 = 0.f, b10 = 0.f, b11 = 0.f;
    for (int jj = w; jj < deg0; jj += 4) {
        int s;
        float p0, p1;
        if (jj < CAP) {
            s = ss[0][jj];
            p0 = se[0][2 * jj];
            p1 = se[0][2 * jj + 1];
        } else {
            s = srcc0[beg0 + jj];
            float2 ev = ((const float2*)el0)[s];
            p0 = __expf(lrelu(ev.x + er00) - fin_m[0]) * fin_inv[0];
            p1 = __expf(lrelu(ev.y + er01) - fin_m[1]) * fin_inv[1];
        }
        unsigned pk = xp[s * 64 + lane];
        float v0 = bf2f((bf16_t)(pk & 0xffffu));
        float v1 = bf2f((bf16_t)(pk >> 16));
        a00 += p0 * v0; a01 += p0 * v1;
        a10 += p1 * v0; a11 += p1 * v1;
    }
    for (int jj = w; jj < deg1; jj += 4) {
        int s;
        float p0, p1;
        if (jj < CAP) {
            s = ss[1][jj];
            p0 = se[1][2 * jj];
            p1 = se[1][2 * jj + 1];
        } else {
            s = srcc1[beg1 + jj];
            float2 ev = ((const float2*)el1)[s];
            p0 = __expf(lrelu(ev.x + er10) - fin_m[2]) * fin_inv[2];
            p1 = __expf(lrelu(ev.y + er11) - fin_m[3]) * fin_inv[3];
        }
        unsigned pk = xp[s * 64 + lane];
        float v0 = bf2f((bf16_t)(pk & 0xffffu));
        float v1 = bf2f((bf16_t)(pk >> 16));
        b00 += p0 * v0; b01 += p0 * v1;
        b10 += p1 * v0; b11 += p1 * v1;
    }
    sh[w][0 + 2 * lane] = a00;       sh[w][0 + 2 * lane + 1] = a01;
    sh[w][128 + 2 * lane] = a10;     sh[w][128 + 2 * lane + 1] = a11;
    sh[w][256 + 2 * lane] = b00;     sh[w][256 + 2 * lane + 1] = b01;
    sh[w][384 + 2 * lane] = b10;     sh[w][384 + 2 * lane + 1] = b11;
    __syncthreads();
#pragma unroll
    for (int rep = 0; rep < 2; ++rep) {
        int o = t + rep * 256;
        float v = sh[0][o] + sh[1][o] + sh[2][o] + sh[3][o];
        y1[(size_t)d * 512 + o] = f2bf(v);
    }
}

// ---------------- agg2: softmax + gather h1 rows -> y2[N,1024] --------------
__global__ void agg2_kernel(
    const int* __restrict__ offs0, const int* __restrict__ srcc0,
    const float* __restrict__ el0, const float* __restrict__ er0,
    const int* __restrict__ offs1, const int* __restrict__ srcc1,
    const float* __restrict__ el1, const float* __restrict__ er1,
    const bf16_t* __restrict__ h1, bf16_t* __restrict__ y2) {
    constexpr int CAP = 64;
    __shared__ float sh[4][1024];
    __shared__ int   ss[2][CAP];
    __shared__ float se[2][2 * CAP];
    __shared__ float fin_m[4], fin_inv[4];
    int d = blockIdx.x;
    int t = threadIdx.x;
    int w = t >> 6, lane = t & 63;
    int beg0 = offs0[d], deg0 = offs0[d + 1] - beg0;
    int beg1 = offs1[d], deg1 = offs1[d + 1] - beg1;
    int c0 = min(deg0, CAP), c1 = min(deg1, CAP);
    float er00 = er0[d * 2], er01 = er0[d * 2 + 1];
    float er10 = er1[d * 2], er11 = er1[d * 2 + 1];

    for (int j = t; j < c0; j += 256) {
        int s = srcc0[beg0 + j];
        ss[0][j] = s;
        float2 ev = ((const float2*)el0)[s];
        se[0][2 * j] = lrelu(ev.x + er00);
        se[0][2 * j + 1] = lrelu(ev.y + er01);
    }
    for (int j = t; j < c1; j += 256) {
        int s = srcc1[beg1 + j];
        ss[1][j] = s;
        float2 ev = ((const float2*)el1)[s];
        se[1][2 * j] = lrelu(ev.x + er10);
        se[1][2 * j + 1] = lrelu(ev.y + er11);
    }
    __syncthreads();
    if (w < 2) {
        int rel = w;
        int head = lane & 1;
        int cc = rel ? c1 : c0;
        int deg = rel ? deg1 : deg0;
        int beg = rel ? beg1 : beg0;
        const int* sc = rel ? srcc1 : srcc0;
        const float* elp = rel ? el1 : el0;
        float erh = rel ? (head ? er11 : er10) : (head ? er01 : er00);
        float m = -1e30f, s = 0.f;
        for (int j = lane >> 1; j < cc; j += 32) {
            float e = se[rel][2 * j + head];
            float mn = fmaxf(m, e);
            s = s * __expf(m - mn) + __expf(e - mn);
            m = mn;
        }
        for (int j = cc + (lane >> 1); j < deg; j += 32) {
            int sv = sc[beg + j];
            float e = lrelu(elp[sv * 2 + head] + erh);
            float mn = fmaxf(m, e);
            s = s * __expf(m - mn) + __expf(e - mn);
            m = mn;
        }
#pragma unroll
        for (int off = 2; off < 64; off <<= 1) {
            float om = __shfl_xor(m, off);
            float os = __shfl_xor(s, off);
            float mn = fmaxf(m, om);
            s = s * __expf(m - mn) + os * __expf(om - mn);
            m = mn;
        }
        if (lane < 2) {
            fin_m[rel * 2 + head] = m;
            fin_inv[rel * 2 + head] = 1.f / fmaxf(s, 1e-9f);
        }
    }
    __syncthreads();
    for (int i = t; i < 2 * c0; i += 256)
        se[0][i] = __expf(se[0][i] - fin_m[i & 1]) * fin_inv[i & 1];
    for (int i = t; i < 2 * c1; i += 256)
        se[1][i] = __expf(se[1][i] - fin_m[2 + (i & 1)]) * fin_inv[2 + (i & 1)];
    __syncthreads();

    const uint2* hp = (const uint2*)h1;
    float a0[4] = {}, a1[4] = {};
    float b0v[4] = {}, b1v[4] = {};
    for (int jj = w; jj < deg0; jj += 4) {
        int s;
        float p0, p1;
        if (jj < CAP) {
            s = ss[0][jj];
            p0 = se[0][2 * jj];
            p1 = se[0][2 * jj + 1];
        } else {
            s = srcc0[beg0 + jj];
            float2 ev = ((const float2*)el0)[s];
            p0 = __expf(lrelu(ev.x + er00) - fin_m[0]) * fin_inv[0];
            p1 = __expf(lrelu(ev.y + er01) - fin_m[1]) * fin_inv[1];
        }
        uint2 pk = hp[s * 64 + lane];
        float v0 = bf2f((bf16_t)(pk.x & 0xffffu));
        float v1 = bf2f((bf16_t)(pk.x >> 16));
        float v2 = bf2f((bf16_t)(pk.y & 0xffffu));
        float v3 = bf2f((bf16_t)(pk.y >> 16));
        a0[0] += p0 * v0; a0[1] += p0 * v1; a0[2] += p0 * v2; a0[3] += p0 * v3;
        a1[0] += p1 * v0; a1[1] += p1 * v1; a1[2] += p1 * v2; a1[3] += p1 * v3;
    }
    for (int jj = w; jj < deg1; jj += 4) {
        int s;
        float p0, p1;
        if (jj < CAP) {
            s = ss[1][jj];
            p0 = se[1][2 * jj];
            p1 = se[1][2 * jj + 1];
        } else {
            s = srcc1[beg1 + jj];
            float2 ev = ((const float2*)el1)[s];
            p0 = __expf(lrelu(ev.x + er10) - fin_m[2]) * fin_inv[2];
            p1 = __expf(lrelu(ev.y + er11) - fin_m[3]) * fin_inv[3];
        }
        uint2 pk = hp[s * 64 + lane];
        float v0 = bf2f((bf16_t)(pk.x & 0xffffu));
        float v1 = bf2f((bf16_t)(pk.x >> 16));
        float v2 = bf2f((bf16_t)(pk.y & 0xffffu));
        float v3 = bf2f((bf16_t)(pk.y >> 16));
        b0v[0] += p0 * v0; b0v[1] += p0 * v1; b0v[2] += p0 * v2; b0v[3] += p0 * v3;
        b1v[0] += p1 * v0; b1v[1] += p1 * v1; b1v[2] += p1 * v2; b1v[3] += p1 * v3;
    }
#pragma unroll
    for (int k = 0; k < 4; ++k) {
        sh[w][0 + 4 * lane + k] = a0[k];
        sh[w][256 + 4 * lane + k] = a1[k];
        sh[w][512 + 4 * lane + k] = b0v[k];
        sh[w][768 + 4 * lane + k] = b1v[k];
    }
    __syncthreads();
#pragma unroll
    for (int rep = 0; rep < 4; ++rep) {
        int o = t + rep * 256;
        float v = sh[0][o] + sh[1][o] + sh[2][o] + sh[3][o];
        y2[(size_t)d * 1024 + o] = f2bf(v);
    }
}

// -------- gemm1: h1 = relu(y1 @ Wc1 + bc1); epilogue: el2/er2 atomics --------
__global__ void gemm1_kernel(const bf16_t* __restrict__ A, const bf16_t* __restrict__ Wf,
                             const float* __restrict__ bc1, bf16_t* __restrict__ h1,
                             const float* __restrict__ wal2, const float* __restrict__ war2,
                             float* __restrict__ el2_0, float* __restrict__ er2_0,
                             float* __restrict__ el2_1, float* __restrict__ er2_1,
                             int n) {
    constexpr int K = 512, M = 256, KS = 16;
    int w = threadIdx.x >> 6, lane = threadIdx.x & 63;
    int q = lane >> 4, m16 = lane & 15;
    int rf = blockIdx.y * 64 + w * 16;
    if (rf >= n) return;
    f32x4 acc[4] = {};
    const bf16_t* Arow = A + (size_t)(rf + m16) * K + q * 8;
    for (int ks = 0; ks < KS; ++ks) {
        short8 af = *(const short8*)(Arow + ks * 32);
#pragma unroll
        for (int f = 0; f < 4; ++f) {
            int ct = blockIdx.x * 4 + f;
            short8 bfr = *(const short8*)(Wf + ((size_t)(ct * KS + ks) * 64 + lane) * 8);
            acc[f] = __builtin_amdgcn_mfma_f32_16x16x32_bf16(af, bfr, acc[f], 0, 0, 0);
        }
    }
    int col0 = blockIdx.x * 64;
    float del[2][2][4] = {};
    float der[2][2][4] = {};
#pragma unroll
    for (int f = 0; f < 4; ++f) {
        int col = col0 + f * 16 + m16;
        float bcv = bc1[col];
        float wle[2][2], wre[2][2];
#pragma unroll
        for (int rel = 0; rel < 2; ++rel)
#pragma unroll
            for (int h = 0; h < 2; ++h) {
                wle[rel][h] = wal2[(rel * 2 + h) * 256 + col];
                wre[rel][h] = war2[(rel * 2 + h) * 256 + col];
            }
#pragma unroll
        for (int r = 0; r < 4; ++r) {
            int row = rf + q * 4 + r;
            float v = fmaxf(acc[f][r] + bcv, 0.f);
            bf16_t hb = f2bf(v);
            h1[(size_t)row * M + col] = hb;
            float vb = bf2f(hb);
#pragma unroll
            for (int rel = 0; rel < 2; ++rel)
#pragma unroll
                for (int h = 0; h < 2; ++h) {
                    del[rel][h][r] += vb * wle[rel][h];
                    der[rel][h][r] += vb * wre[rel][h];
                }
        }
    }
#pragma unroll
    for (int off = 1; off < 16; off <<= 1) {
#pragma unroll
        for (int rel = 0; rel < 2; ++rel)
#pragma unroll
            for (int h = 0; h < 2; ++h)
#pragma unroll
                for (int r = 0; r < 4; ++r) {
                    del[rel][h][r] += __shfl_xor(del[rel][h][r], off);
                    der[rel][h][r] += __shfl_xor(der[rel][h][r], off);
                }
    }
    if (m16 == 0) {
#pragma unroll
        for (int r = 0; r < 4; ++r) {
            int row = rf + q * 4 + r;
            atomicAdd(&el2_0[row * 2 + 0], del[0][0][r]);
            atomicAdd(&el2_0[row * 2 + 1], del[0][1][r]);
            atomicAdd(&el2_1[row * 2 + 0], del[1][0][r]);
            atomicAdd(&el2_1[row * 2 + 1], del[1][1][r]);
            atomicAdd(&er2_0[row * 2 + 0], der[0][0][r]);
            atomicAdd(&er2_0[row * 2 + 1], der[0][1][r]);
            atomicAdd(&er2_1[row * 2 + 0], der[1][0][r]);
            atomicAdd(&er2_1[row * 2 + 1], der[1][1][r]);
        }
    }
}

// -------- gemm2: out = y2 @ Wc2 + bc2 (final store, flag dtype) --------
__global__ void gemm2_kernel(const bf16_t* __restrict__ A, const bf16_t* __restrict__ Wf,
                             const float* __restrict__ bc2, void* __restrict__ out,
                             const int* __restrict__ flag, int n) {
    constexpr int K = 1024, M = 128, KS = 32;
    int w = threadIdx.x >> 6, lane = threadIdx.x & 63;
    int q = lane >> 4, m16 = lane & 15;
    int rf = blockIdx.y * 64 + w * 16;
    if (rf >= n) return;
    f32x4 acc[4] = {};
    const bf16_t* Arow = A + (size_t)(rf + m16) * K + q * 8;
    for (int ks = 0; ks < KS; ++ks) {
        short8 af = *(const short8*)(Arow + ks * 32);
#pragma unroll
        for (int f = 0; f < 4; ++f) {
            int ct = blockIdx.x * 4 + f;
            short8 bfr = *(const short8*)(Wf + ((size_t)(ct * KS + ks) * 64 + lane) * 8);
            acc[f] = __builtin_amdgcn_mfma_f32_16x16x32_bf16(af, bfr, acc[f], 0, 0, 0);
        }
    }
    int col0 = blockIdx.x * 64;
    int fl = *flag;
#pragma unroll
    for (int f = 0; f < 4; ++f) {
        int col = col0 + f * 16 + m16;
        float bcv = bc2[col];
#pragma unroll
        for (int r = 0; r < 4; ++r) {
            int row = rf + q * 4 + r;
            float v = acc[f][r] + bcv;
            if (fl) ((float*)out)[(size_t)row * M + col] = v;
            else    ((bf16_t*)out)[(size_t)row * M + col] = f2bf(v);
        }
    }
}

extern "C" void kernel_launch(void* const* d_in, const int* in_sizes, int n_in,
                              void* d_out, int out_size, void* d_ws, size_t ws_size,
                              hipStream_t stream) {
    (void)in_sizes; (void)n_in; (void)out_size; (void)ws_size;
    const int* src0 = (const int*)d_in[1];
    const int* dst0 = (const int*)d_in[2];
    const int* src1 = (const int*)d_in[3];
    const int* dst1 = (const int*)d_in[4];

    char* ws = (char*)d_ws;
    size_t off = 0;
    auto alloc = [&](size_t bytes) -> void* {
        void* p = ws + off;
        off = (off + bytes + 255) & ~(size_t)255;
        return p;
    };
    int* flag = (int*)alloc(4);
    static const int tn[NT] = {NN * 128,
                               128 * 512, 512, 512, 512,
                               128 * 512, 512, 512, 512,
                               256 * 256, 256, 256, 256,
                               256 * 256, 256, 256, 256};
    bf16_t* tb[NT];
    for (int i = 0; i < NT; ++i) tb[i] = (bf16_t*)alloc((size_t)tn[i] * 2);
    bf16_t* xb = tb[0];

    bf16_t* Wc1f = (bf16_t*)alloc((size_t)512 * 256 * 2);
    bf16_t* Wc2f = (bf16_t*)alloc((size_t)1024 * 128 * 2);
    float* wal1 = (float*)alloc(512 * 4);
    float* war1 = (float*)alloc(512 * 4);
    float* wal2 = (float*)alloc(1024 * 4);
    float* war2 = (float*)alloc(1024 * 4);
    float* bc1  = (float*)alloc(256 * 4);
    float* bc2  = (float*)alloc(128 * 4);

    // zero region: cnt0, cnt1, el2/er2 (atomic targets)
    char* zbeg = ws + off;
    int* cnt0 = (int*)alloc(NN * 4);
    int* cnt1 = (int*)alloc(NN * 4);
    float* el2_0 = (float*)alloc(NN * 2 * 4);
    float* er2_0 = (float*)alloc(NN * 2 * 4);
    float* el2_1 = (float*)alloc(NN * 2 * 4);
    float* er2_1 = (float*)alloc(NN * 2 * 4);
    char* zend = ws + off;
    int zcount = (int)((zend - zbeg) >> 2);

    int* offs0 = (int*)alloc((NN + 1) * 4);
    int* offs1 = (int*)alloc((NN + 1) * 4);
    int* cur0  = (int*)alloc(NN * 4);
    int* cur1  = (int*)alloc(NN * 4);
    int* srcc0 = (int*)alloc(NE * 4);
    int* srcc1 = (int*)alloc(NE * 4);
    float* el1_0 = (float*)alloc(NN * 2 * 4);
    float* er1_0 = (float*)alloc(NN * 2 * 4);
    float* el1_1 = (float*)alloc(NN * 2 * 4);
    float* er1_1 = (float*)alloc(NN * 2 * 4);
    bf16_t* h1 = (bf16_t*)alloc((size_t)NN * 256 * 2);
    bf16_t* Y  = (bf16_t*)alloc((size_t)NN * 1024 * 2);
    bf16_t* y1 = Y;
    bf16_t* y2 = Y;

    // ---- 1. convert + zero + inline dtype detect ----
    CzArgs cz;
    static const int din_idx[NT] = {0, 5, 6, 7, 8, 9, 10, 11, 12,
                                    13, 14, 15, 16, 17, 18, 19, 20};
    int total_blocks = 0;
    for (int i = 0; i < NT; ++i) {
        cz.src[i] = d_in[din_idx[i]];
        cz.dst[i] = tb[i];
        cz.n[i] = tn[i];
        cz.nblk[i] = (tn[i] + 255) / 256;
        total_blocks += cz.nblk[i];
    }
    cz.zero_ptr = (int*)zbeg;
    cz.zn = zcount;
    cz.nblk[NT] = (zcount + 255) / 256;
    total_blocks += cz.nblk[NT];
    cz.xsrc = (const unsigned*)d_in[0];
    cz.flag_out = flag;
    convzero_kernel<<<total_blocks, 256, 0, stream>>>(cz);

    // ---- 2. prep + hist ----
    PhArgs ph;
    ph.p.W1[0] = tb[1];  ph.p.W1[1] = tb[5];
    ph.p.W2[0] = tb[9];  ph.p.W2[1] = tb[13];
    ph.p.al1[0] = tb[2]; ph.p.ar1[0] = tb[3];
    ph.p.al1[1] = tb[6]; ph.p.ar1[1] = tb[7];
    ph.p.al2[0] = tb[10]; ph.p.ar2[0] = tb[11];
    ph.p.al2[1] = tb[14]; ph.p.ar2[1] = tb[15];
    ph.p.b1[0] = tb[4];  ph.p.b1[1] = tb[8];
    ph.p.b2[0] = tb[12]; ph.p.b2[1] = tb[16];
    ph.p.wal1 = wal1; ph.p.war1 = war1;
    ph.p.wal2 = wal2; ph.p.war2 = war2;
    ph.p.bc1 = bc1; ph.p.bc2 = bc2;
    ph.p.Wc1f = Wc1f; ph.p.Wc2f = Wc2f;
    ph.c.src[0] = src0; ph.c.src[1] = src1;
    ph.c.dst[0] = dst0; ph.c.dst[1] = dst1;
    ph.c.cnt[0] = cnt0; ph.c.cnt[1] = cnt1;
    ph.c.offs[0] = offs0; ph.c.offs[1] = offs1;
    ph.c.cursor[0] = cur0; ph.c.cursor[1] = cur1;
    ph.c.srcc[0] = srcc0; ph.c.srcc[1] = srcc1;
    prep_hist_kernel<<<142 + 2500, 256, 0, stream>>>(ph);

    // ---- 3. scan ----
    scan2_kernel<<<2, 256, 0, stream>>>(ph.c, NN);

    // ---- 4. scatter + elr1 ----
    scat_elr_kernel<<<5000 + 2500, 256, 0, stream>>>(
        ph.c, xb, wal1, war1, el1_0, er1_0, el1_1, er1_1);

    // ---- 5. agg1 ----
    agg1_kernel<<<NN, 256, 0, stream>>>(offs0, srcc0, el1_0, er1_0,
                                        offs1, srcc1, el1_1, er1_1, xb, y1);

    // ---- 6. gemm1 ----
    gemm1_kernel<<<dim3(4, 313), 256, 0, stream>>>(
        y1, Wc1f, bc1, h1, wal2, war2, el2_0, er2_0, el2_1, er2_1, NN);

    // ---- 7. agg2 ----
    agg2_kernel<<<NN, 256, 0, stream>>>(offs0, srcc0, el2_0, er2_0,
                                        offs1, srcc1, el2_1, er2_1, h1, y2);

    // ---- 8. gemm2 ----
    gemm2_kernel<<<dim3(2, 313), 256, 0, stream>>>(y2, Wc2f, bc2, d_out, flag, NN);
}

// Round 9
// 427.736 us; speedup vs baseline: 1.4219x; 1.0420x over previous
//
#include <hip/hip_runtime.h>

// RGAT: 2-layer, 2-relation GAT. N=20000, E=320000/rel, D=128, H=2.
// Round 9: (1) layer-2 re-commuted: z_rel = h1 @ (0.5*W2_rel) [N,256] via MFMA
// (grid.z=2), final agg gathers z rows and writes d_out directly (y2 41MB
// round-trip eliminated; per-edge FMA halved). (2) x never converted:
// consumers dual-path (bf16/fp32) on the device dtype flag.

#define NN 20000
#define NE 320000

typedef unsigned short bf16_t;
typedef __attribute__((ext_vector_type(8))) short short8;
typedef __attribute__((ext_vector_type(4))) float f32x4;

__device__ __forceinline__ float bf2f(bf16_t u) {
    return __uint_as_float(((unsigned)u) << 16);
}
__device__ __forceinline__ bf16_t f2bf(float f) {
    unsigned x = __float_as_uint(f);
    unsigned r = (x + 0x7fffu + ((x >> 16) & 1u)) >> 16;   // RNE
    return (bf16_t)r;
}
__device__ __forceinline__ float lrelu(float v) {
    return (v > 0.f) ? v : 0.2f * v;
}
// x row access: dword-pair idx = node*64 + lane -> dims 2i, 2i+1 (both dtypes)
__device__ __forceinline__ void load_x2(const void* x, int flag, int idx,
                                        float& v0, float& v1) {
    if (flag) {
        float2 f = ((const float2*)x)[idx];
        v0 = f.x; v1 = f.y;
    } else {
        unsigned pk = ((const unsigned*)x)[idx];
        v0 = bf2f((bf16_t)(pk & 0xffffu));
        v1 = bf2f((bf16_t)(pk >> 16));
    }
}

// ------------- convert 16 float tensors (weights) to bf16 + zero region -----
#define NTC 16
struct CzArgs {
    const void* src[NTC];
    bf16_t* dst[NTC];
    int n[NTC];
    int nblk[NTC + 1];
    int* zero_ptr;
    int zn;
    const unsigned* xsrc;
    int* flag_out;
};
__global__ void convzero_kernel(CzArgs a) {
    __shared__ int fl_s;
    int t = threadIdx.x;
    if (t < 64) {
        float mx = 0.f;
        for (int i = t; i < 256; i += 64) {
            float v = fabsf(bf2f((bf16_t)(a.xsrc[i] & 0xffffu)));
            v = (v <= 1e30f) ? v : 1e30f;
            mx = fmaxf(mx, v);
        }
        for (int off = 32; off > 0; off >>= 1) mx = fmaxf(mx, __shfl_xor(mx, off));
        if (t == 0) {
            int f = (mx > 1e6f) ? 1 : 0;
            fl_s = f;
            if (blockIdx.x == 0) *a.flag_out = f;
        }
    }
    __syncthreads();
    int flag = fl_s;
    int b = blockIdx.x;
    int ti = 0;
#pragma unroll 1
    for (; ti <= NTC; ++ti) {
        if (b < a.nblk[ti]) break;
        b -= a.nblk[ti];
    }
    int i = b * 256 + t;
    if (ti < NTC) {
        if (i < a.n[ti]) {
            if (flag) a.dst[ti][i] = f2bf(((const float*)a.src[ti])[i]);
            else      a.dst[ti][i] = ((const bf16_t*)a.src[ti])[i];
        }
    } else {
        if (i < a.zn) a.zero_ptr[i] = 0;
    }
}

// ---------------- prep: wal/war vectors, biases, frag repacks ----------------
struct PrepArgs {
    const bf16_t *W1[2], *W2[2];
    const bf16_t *al1[2], *ar1[2], *al2[2], *ar2[2];
    const bf16_t *b1[2], *b2[2];
    float *wal1, *war1;     // [2rel*2h*128]
    float *wal2, *war2;     // [2rel*2h*256]
    float *bc1, *bc2;       // [256], [128]
    bf16_t *Wc1f;           // combined layer-1 weight, frag order (K=512,M=256)
    bf16_t *Wzf;            // per-rel 0.5*W2 frag tables (K=256,M=256) x2
};
// bx: [0,4) wal1/war1 | [4,12) wal2/war2 | [12,14) bc | [14,78) Wc1f | [78,142) Wzf
__device__ __forceinline__ void prep_body(const PrepArgs& p, int bx, int tid) {
    if (bx < 4) {
        int t = bx * 256 + tid;
        int lr = t >> 9, rel = (t >> 8) & 1, h = (t >> 7) & 1, k = t & 127;
        const bf16_t* av = lr ? p.ar1[rel] : p.al1[rel];
        const bf16_t* W = p.W1[rel];
        float s = 0.f;
        for (int o = 0; o < 256; ++o)
            s += bf2f(W[k * 512 + h * 256 + o]) * bf2f(av[h * 256 + o]);
        (lr ? p.war1 : p.wal1)[(rel * 2 + h) * 128 + k] = s;
    } else if (bx < 12) {
        int t = (bx - 4) * 256 + tid;
        int lr = t >> 10, rel = (t >> 9) & 1, h = (t >> 8) & 1, k = t & 255;
        const bf16_t* av = lr ? p.ar2[rel] : p.al2[rel];
        const bf16_t* W = p.W2[rel];
        float s = 0.f;
        for (int o = 0; o < 128; ++o)
            s += bf2f(W[k * 256 + h * 128 + o]) * bf2f(av[h * 128 + o]);
        (lr ? p.war2 : p.wal2)[(rel * 2 + h) * 256 + k] = s;
    } else if (bx < 14) {
        int t = (bx - 12) * 256 + tid;
        if (t < 256) {
            p.bc1[t] = 0.5f * (bf2f(p.b1[0][t]) + bf2f(p.b1[0][256 + t]) +
                               bf2f(p.b1[1][t]) + bf2f(p.b1[1][256 + t]));
        } else if (t < 384) {
            int o = t - 256;
            p.bc2[o] = 0.5f * (bf2f(p.b2[0][o]) + bf2f(p.b2[0][128 + o]) +
                               bf2f(p.b2[1][o]) + bf2f(p.b2[1][128 + o]));
        }
    } else if (bx < 78) {               // Wc1f: K=512, M=256, KS=16
        int i = (bx - 14) * 256 + tid;  // [0, 16384)
        int lane = i & 63;
        int t2 = i >> 6;
        int ct = t2 >> 4, ks = t2 & 15;
        int col = ct * 16 + (lane & 15);
        bf16_t* out = p.Wc1f + (size_t)i * 8;
#pragma unroll
        for (int j = 0; j < 8; ++j) {
            int r = ks * 32 + ((lane >> 4) << 3) + j;   // [0,512)
            int rel = r >> 8, h = (r >> 7) & 1, kx = r & 127;
            out[j] = f2bf(0.5f * bf2f(p.W1[rel][kx * 512 + h * 256 + col]));
        }
    } else {                            // Wzf: per rel K=256, M=256, KS=8
        int b = bx - 78;                // [0,64)
        int rel = b >> 5;
        int i = (b & 31) * 256 + tid;   // [0, 8192)
        int lane = i & 63;
        int t2 = i >> 6;                // ct*8 + ks
        int ct = t2 >> 3, ks = t2 & 7;
        int col = ct * 16 + (lane & 15);
        bf16_t* out = p.Wzf + (size_t)rel * 65536 + (size_t)i * 8;
#pragma unroll
        for (int j = 0; j < 8; ++j) {
            int r = ks * 32 + ((lane >> 4) << 3) + j;   // k in [0,256)
            out[j] = f2bf(0.5f * bf2f(p.W2[rel][r * 256 + col]));
        }
    }
}

// ---------------- CSR build ----------------
struct Csr2 {
    const int* src[2];
    const int* dst[2];
    int* cnt[2];
    int* offs[2];
    int* cursor[2];
    int* srcc[2];
};
struct PhArgs { PrepArgs p; Csr2 c; };
__global__ void prep_hist_kernel(PhArgs a) {
    int bx = blockIdx.x;
    if (bx < 142) {
        prep_body(a.p, bx, threadIdx.x);
    } else {
        int b = bx - 142;
        int rel = b / 1250;
        int i = (b - rel * 1250) * 256 + threadIdx.x;
        if (i < NE) atomicAdd(&a.c.cnt[rel][a.c.dst[rel][i]], 1);
    }
}

__global__ void scan2_kernel(Csr2 c, int n) {
    int rel = blockIdx.x;
    const int* cnt = c.cnt[rel];
    int* offs = c.offs[rel];
    int* cursor = c.cursor[rel];
    __shared__ int sums[256];
    int t = threadIdx.x;
    int chunk = (n + 255) >> 8;
    int lo = t * chunk;
    int hi = min(lo + chunk, n);
    int s = 0;
    for (int i = lo; i < hi; ++i) s += cnt[i];
    sums[t] = s;
    __syncthreads();
    if (t == 0) {
        int run = 0;
        for (int i = 0; i < 256; ++i) { int v = sums[i]; sums[i] = run; run += v; }
    }
    __syncthreads();
    int run = sums[t];
    for (int i = lo; i < hi; ++i) { int v = cnt[i]; offs[i] = run; cursor[i] = run; run += v; }
    if (t == 255) offs[n] = run;
}

// merged: elr1 (5000 blocks, dual-path x) + scatter (2x1250 blocks)
__global__ void scat_elr_kernel(Csr2 c, const void* __restrict__ x,
                                const int* __restrict__ flagp,
                                const float* __restrict__ wal1,
                                const float* __restrict__ war1,
                                float* __restrict__ el0, float* __restrict__ er0,
                                float* __restrict__ el1, float* __restrict__ er1) {
    __shared__ float wl[512], wr[512];
    int t = threadIdx.x;
    if (blockIdx.x < 5000) {
        wl[t] = wal1[t]; wl[t + 256] = wal1[t + 256];
        wr[t] = war1[t]; wr[t + 256] = war1[t + 256];
        __syncthreads();
        int fl = *flagp;
        int w = t >> 6, lane = t & 63;
        int node = blockIdx.x * 4 + w;
        float v0, v1;
        load_x2(x, fl, node * 64 + lane, v0, v1);
        float de[4], dr[4];
#pragma unroll
        for (int cch = 0; cch < 4; ++cch) {
            de[cch] = v0 * wl[cch * 128 + 2 * lane] + v1 * wl[cch * 128 + 2 * lane + 1];
            dr[cch] = v0 * wr[cch * 128 + 2 * lane] + v1 * wr[cch * 128 + 2 * lane + 1];
        }
#pragma unroll
        for (int off = 32; off > 0; off >>= 1) {
#pragma unroll
            for (int cch = 0; cch < 4; ++cch) {
                de[cch] += __shfl_xor(de[cch], off);
                dr[cch] += __shfl_xor(dr[cch], off);
            }
        }
        if (lane == 0) {
            el0[node * 2 + 0] = de[0]; el0[node * 2 + 1] = de[1];
            el1[node * 2 + 0] = de[2]; el1[node * 2 + 1] = de[3];
            er0[node * 2 + 0] = dr[0]; er0[node * 2 + 1] = dr[1];
            er1[node * 2 + 0] = dr[2]; er1[node * 2 + 1] = dr[3];
        }
    } else {
        int b = blockIdx.x - 5000;
        int rel = b / 1250;
        int i = (b - rel * 1250) * 256 + t;
        if (i < NE) {
            int p = atomicAdd(&c.cursor[rel][c.dst[rel][i]], 1);
            c.srcc[rel][p] = c.src[rel][i];
        }
    }
}

// ---------------- agg1: softmax + gather x rows -> y1[N,512] ----------------
__global__ void agg1_kernel(
    const int* __restrict__ offs0, const int* __restrict__ srcc0,
    const float* __restrict__ el0, const float* __restrict__ er0,
    const int* __restrict__ offs1, const int* __restrict__ srcc1,
    const float* __restrict__ el1, const float* __restrict__ er1,
    const void* __restrict__ x, const int* __restrict__ flagp,
    bf16_t* __restrict__ y1) {
    constexpr int CAP = 64;
    __shared__ float sh[4][512];
    __shared__ int   ss[2][CAP];
    __shared__ float se[2][2 * CAP];
    __shared__ float fin_m[4], fin_inv[4];
    int d = blockIdx.x;
    int t = threadIdx.x;
    int w = t >> 6, lane = t & 63;
    int beg0 = offs0[d], deg0 = offs0[d + 1] - beg0;
    int beg1 = offs1[d], deg1 = offs1[d + 1] - beg1;
    int c0 = min(deg0, CAP), c1 = min(deg1, CAP);
    float er00 = er0[d * 2], er01 = er0[d * 2 + 1];
    float er10 = er1[d * 2], er11 = er1[d * 2 + 1];

    for (int j = t; j < c0; j += 256) {
        int s = srcc0[beg0 + j];
        ss[0][j] = s;
        float2 ev = ((const float2*)el0)[s];
        se[0][2 * j] = lrelu(ev.x + er00);
        se[0][2 * j + 1] = lrelu(ev.y + er01);
    }
    for (int j = t; j < c1; j += 256) {
        int s = srcc1[beg1 + j];
        ss[1][j] = s;
        float2 ev = ((const float2*)el1)[s];
        se[1][2 * j] = lrelu(ev.x + er10);
        se[1][2 * j + 1] = lrelu(ev.y + er11);
    }
    __syncthreads();
    if (w < 2) {
        int rel = w;
        int head = lane & 1;
        int cc = rel ? c1 : c0;
        int deg = rel ? deg1 : deg0;
        int beg = rel ? beg1 : beg0;
        const int* sc = rel ? srcc1 : srcc0;
        const float* elp = rel ? el1 : el0;
        float erh = rel ? (head ? er11 : er10) : (head ? er01 : er00);
        float m = -1e30f, s = 0.f;
        for (int j = lane >> 1; j < cc; j += 32) {
            float e = se[rel][2 * j + head];
            float mn = fmaxf(m, e);
            s = s * __expf(m - mn) + __expf(e - mn);
            m = mn;
        }
        for (int j = cc + (lane >> 1); j < deg; j += 32) {
            int sv = sc[beg + j];
            float e = lrelu(elp[sv * 2 + head] + erh);
            float mn = fmaxf(m, e);
            s = s * __expf(m - mn) + __expf(e - mn);
            m = mn;
        }
#pragma unroll
        for (int off = 2; off < 64; off <<= 1) {
            float om = __shfl_xor(m, off);
            float os = __shfl_xor(s, off);
            float mn = fmaxf(m, om);
            s = s * __expf(m - mn) + os * __expf(om - mn);
            m = mn;
        }
        if (lane < 2) {
            fin_m[rel * 2 + head] = m;
            fin_inv[rel * 2 + head] = 1.f / fmaxf(s, 1e-9f);
        }
    }
    __syncthreads();
    for (int i = t; i < 2 * c0; i += 256)
        se[0][i] = __expf(se[0][i] - fin_m[i & 1]) * fin_inv[i & 1];
    for (int i = t; i < 2 * c1; i += 256)
        se[1][i] = __expf(se[1][i] - fin_m[2 + (i & 1)]) * fin_inv[2 + (i & 1)];
    __syncthreads();

    int fl = *flagp;
    float a00 = 0.f, a01 = 0.f, a10 = 0.f, a11 = 0.f;
    float b00 = 0.f, b01 = 0.f, b10 = 0.f, b11 = 0.f;
    for (int jj = w; jj < deg0; jj += 4) {
        int s;
        float p0, p1;
        if (jj < CAP) {
            s = ss[0][jj];
            p0 = se[0][2 * jj];
            p1 = se[0][2 * jj + 1];
        } else {
            s = srcc0[beg0 + jj];
            float2 ev = ((const float2*)el0)[s];
            p0 = __expf(lrelu(ev.x + er00) - fin_m[0]) * fin_inv[0];
            p1 = __expf(lrelu(ev.y + er01) - fin_m[1]) * fin_inv[1];
        }
        float v0, v1;
        load_x2(x, fl, s * 64 + lane, v0, v1);
        a00 += p0 * v0; a01 += p0 * v1;
        a10 += p1 * v0; a11 += p1 * v1;
    }
    for (int jj = w; jj < deg1; jj += 4) {
        int s;
        float p0, p1;
        if (jj < CAP) {
            s = ss[1][jj];
            p0 = se[1][2 * jj];
            p1 = se[1][2 * jj + 1];
        } else {
            s = srcc1[beg1 + jj];
            float2 ev = ((const float2*)el1)[s];
            p0 = __expf(lrelu(ev.x + er10) - fin_m[2]) * fin_inv[2];
            p1 = __expf(lrelu(ev.y + er11) - fin_m[3]) * fin_inv[3];
        }
        float v0, v1;
        load_x2(x, fl, s * 64 + lane, v0, v1);
        b00 += p0 * v0; b01 += p0 * v1;
        b10 += p1 * v0; b11 += p1 * v1;
    }
    sh[w][0 + 2 * lane] = a00;       sh[w][0 + 2 * lane + 1] = a01;
    sh[w][128 + 2 * lane] = a10;     sh[w][128 + 2 * lane + 1] = a11;
    sh[w][256 + 2 * lane] = b00;     sh[w][256 + 2 * lane + 1] = b01;
    sh[w][384 + 2 * lane] = b10;     sh[w][384 + 2 * lane + 1] = b11;
    __syncthreads();
#pragma unroll
    for (int rep = 0; rep < 2; ++rep) {
        int o = t + rep * 256;
        float v = sh[0][o] + sh[1][o] + sh[2][o] + sh[3][o];
        y1[(size_t)d * 512 + o] = f2bf(v);
    }
}

// -------- gemm1: h1 = relu(y1 @ Wc1 + bc1); epilogue: el2/er2 atomics --------
__global__ void gemm1_kernel(const bf16_t* __restrict__ A, const bf16_t* __restrict__ Wf,
                             const float* __restrict__ bc1, bf16_t* __restrict__ h1,
                             const float* __restrict__ wal2, const float* __restrict__ war2,
                             float* __restrict__ el2_0, float* __restrict__ er2_0,
                             float* __restrict__ el2_1, float* __restrict__ er2_1,
                             int n) {
    constexpr int K = 512, M = 256, KS = 16;
    int w = threadIdx.x >> 6, lane = threadIdx.x & 63;
    int q = lane >> 4, m16 = lane & 15;
    int rf = blockIdx.y * 64 + w * 16;
    if (rf >= n) return;
    f32x4 acc[4] = {};
    const bf16_t* Arow = A + (size_t)(rf + m16) * K + q * 8;
    for (int ks = 0; ks < KS; ++ks) {
        short8 af = *(const short8*)(Arow + ks * 32);
#pragma unroll
        for (int f = 0; f < 4; ++f) {
            int ct = blockIdx.x * 4 + f;
            short8 bfr = *(const short8*)(Wf + ((size_t)(ct * KS + ks) * 64 + lane) * 8);
            acc[f] = __builtin_amdgcn_mfma_f32_16x16x32_bf16(af, bfr, acc[f], 0, 0, 0);
        }
    }
    int col0 = blockIdx.x * 64;
    float del[2][2][4] = {};
    float der[2][2][4] = {};
#pragma unroll
    for (int f = 0; f < 4; ++f) {
        int col = col0 + f * 16 + m16;
        float bcv = bc1[col];
        float wle[2][2], wre[2][2];
#pragma unroll
        for (int rel = 0; rel < 2; ++rel)
#pragma unroll
            for (int h = 0; h < 2; ++h) {
                wle[rel][h] = wal2[(rel * 2 + h) * 256 + col];
                wre[rel][h] = war2[(rel * 2 + h) * 256 + col];
            }
#pragma unroll
        for (int r = 0; r < 4; ++r) {
            int row = rf + q * 4 + r;
            float v = fmaxf(acc[f][r] + bcv, 0.f);
            bf16_t hb = f2bf(v);
            h1[(size_t)row * M + col] = hb;
            float vb = bf2f(hb);
#pragma unroll
            for (int rel = 0; rel < 2; ++rel)
#pragma unroll
                for (int h = 0; h < 2; ++h) {
                    del[rel][h][r] += vb * wle[rel][h];
                    der[rel][h][r] += vb * wre[rel][h];
                }
        }
    }
#pragma unroll
    for (int off = 1; off < 16; off <<= 1) {
#pragma unroll
        for (int rel = 0; rel < 2; ++rel)
#pragma unroll
            for (int h = 0; h < 2; ++h)
#pragma unroll
                for (int r = 0; r < 4; ++r) {
                    del[rel][h][r] += __shfl_xor(del[rel][h][r], off);
                    der[rel][h][r] += __shfl_xor(der[rel][h][r], off);
                }
    }
    if (m16 == 0) {
#pragma unroll
        for (int r = 0; r < 4; ++r) {
            int row = rf + q * 4 + r;
            atomicAdd(&el2_0[row * 2 + 0], del[0][0][r]);
            atomicAdd(&el2_0[row * 2 + 1], del[0][1][r]);
            atomicAdd(&el2_1[row * 2 + 0], del[1][0][r]);
            atomicAdd(&el2_1[row * 2 + 1], del[1][1][r]);
            atomicAdd(&er2_0[row * 2 + 0], der[0][0][r]);
            atomicAdd(&er2_0[row * 2 + 1], der[0][1][r]);
            atomicAdd(&er2_1[row * 2 + 0], der[1][0][r]);
            atomicAdd(&er2_1[row * 2 + 1], der[1][1][r]);
        }
    }
}

// -------- gemmZ: z_rel = h1 @ (0.5*W2_rel)  [N,256] per rel, grid.z=2 --------
__global__ void gemmz_kernel(const bf16_t* __restrict__ A, const bf16_t* __restrict__ Wzf,
                             bf16_t* __restrict__ z, int n) {
    constexpr int K = 256, M = 256, KS = 8;
    int rel = blockIdx.z;
    const bf16_t* Wf = Wzf + (size_t)rel * 65536;
    bf16_t* C = z + (size_t)rel * NN * 256;
    int w = threadIdx.x >> 6, lane = threadIdx.x & 63;
    int q = lane >> 4, m16 = lane & 15;
    int rf = blockIdx.y * 64 + w * 16;
    if (rf >= n) return;
    f32x4 acc[4] = {};
    const bf16_t* Arow = A + (size_t)(rf + m16) * K + q * 8;
    for (int ks = 0; ks < KS; ++ks) {
        short8 af = *(const short8*)(Arow + ks * 32);
#pragma unroll
        for (int f = 0; f < 4; ++f) {
            int ct = blockIdx.x * 4 + f;
            short8 bfr = *(const short8*)(Wf + ((size_t)(ct * KS + ks) * 64 + lane) * 8);
            acc[f] = __builtin_amdgcn_mfma_f32_16x16x32_bf16(af, bfr, acc[f], 0, 0, 0);
        }
    }
    int col0 = blockIdx.x * 64;
#pragma unroll
    for (int f = 0; f < 4; ++f) {
#pragma unroll
        for (int r = 0; r < 4; ++r) {
            int row = rf + q * 4 + r;
            C[(size_t)row * M + col0 + f * 16 + m16] = f2bf(acc[f][r]);
        }
    }
}

// -------- aggout: softmax + gather z rows -> out[N,128] directly --------
// One dst per block, 4 waves. z row = 256 bf16 [h*128+o]; lane reads uint2
// (dims 4(l%32)..+3 of head l/32). Per edge: single-head alpha, 4 FMA/lane.
__global__ void aggout_kernel(
    const int* __restrict__ offs0, const int* __restrict__ srcc0,
    const float* __restrict__ el0, const float* __restrict__ er0,
    const int* __restrict__ offs1, const int* __restrict__ srcc1,
    const float* __restrict__ el1, const float* __restrict__ er1,
    const bf16_t* __restrict__ z, const float* __restrict__ bc2,
    void* __restrict__ out, const int* __restrict__ flagp) {
    constexpr int CAP = 64;
    __shared__ float sh[4][256];
    __shared__ int   ss[2][CAP];
    __shared__ float se[2][2 * CAP];
    __shared__ float fin_m[4], fin_inv[4];
    int d = blockIdx.x;
    int t = threadIdx.x;
    int w = t >> 6, lane = t & 63;
    int beg0 = offs0[d], deg0 = offs0[d + 1] - beg0;
    int beg1 = offs1[d], deg1 = offs1[d + 1] - beg1;
    int c0 = min(deg0, CAP), c1 = min(deg1, CAP);
    float er00 = er0[d * 2], er01 = er0[d * 2 + 1];
    float er10 = er1[d * 2], er11 = er1[d * 2 + 1];

    for (int j = t; j < c0; j += 256) {
        int s = srcc0[beg0 + j];
        ss[0][j] = s;
        float2 ev = ((const float2*)el0)[s];
        se[0][2 * j] = lrelu(ev.x + er00);
        se[0][2 * j + 1] = lrelu(ev.y + er01);
    }
    for (int j = t; j < c1; j += 256) {
        int s = srcc1[beg1 + j];
        ss[1][j] = s;
        float2 ev = ((const float2*)el1)[s];
        se[1][2 * j] = lrelu(ev.x + er10);
        se[1][2 * j + 1] = lrelu(ev.y + er11);
    }
    __syncthreads();
    if (w < 2) {
        int rel = w;
        int head = lane & 1;
        int cc = rel ? c1 : c0;
        int deg = rel ? deg1 : deg0;
        int beg = rel ? beg1 : beg0;
        const int* sc = rel ? srcc1 : srcc0;
        const float* elp = rel ? el1 : el0;
        float erh = rel ? (head ? er11 : er10) : (head ? er01 : er00);
        float m = -1e30f, s = 0.f;
        for (int j = lane >> 1; j < cc; j += 32) {
            float e = se[rel][2 * j + head];
            float mn = fmaxf(m, e);
            s = s * __expf(m - mn) + __expf(e - mn);
            m = mn;
        }
        for (int j = cc + (lane >> 1); j < deg; j += 32) {
            int sv = sc[beg + j];
            float e = lrelu(elp[sv * 2 + head] + erh);
            float mn = fmaxf(m, e);
            s = s * __expf(m - mn) + __expf(e - mn);
            m = mn;
        }
#pragma unroll
        for (int off = 2; off < 64; off <<= 1) {
            float om = __shfl_xor(m, off);
            float os = __shfl_xor(s, off);
            float mn = fmaxf(m, om);
            s = s * __expf(m - mn) + os * __expf(om - mn);
            m = mn;
        }
        if (lane < 2) {
            fin_m[rel * 2 + head] = m;
            fin_inv[rel * 2 + head] = 1.f / fmaxf(s, 1e-9f);
        }
    }
    __syncthreads();
    for (int i = t; i < 2 * c0; i += 256)
        se[0][i] = __expf(se[0][i] - fin_m[i & 1]) * fin_inv[i & 1];
    for (int i = t; i < 2 * c1; i += 256)
        se[1][i] = __expf(se[1][i] - fin_m[2 + (i & 1)]) * fin_inv[2 + (i & 1)];
    __syncthreads();

    int head = lane >> 5;                 // lanes 0-31 head 0, 32-63 head 1
    float acc[4] = {};
    {
        const uint2* zp = (const uint2*)z;
        float erh = head ? er01 : er00;
        float fmh = fin_m[head], fih = fin_inv[head];
        for (int jj = w; jj < deg0; jj += 4) {
            int s;
            float a;
            if (jj < CAP) {
                s = ss[0][jj];
                a = se[0][2 * jj + head];
            } else {
                s = srcc0[beg0 + jj];
                float2 ev = ((const float2*)el0)[s];
                a = __expf(lrelu((head ? ev.y : ev.x) + erh) - fmh) * fih;
            }
            uint2 pk = zp[s * 64 + lane];
            acc[0] += a * bf2f((bf16_t)(pk.x & 0xffffu));
            acc[1] += a * bf2f((bf16_t)(pk.x >> 16));
            acc[2] += a * bf2f((bf16_t)(pk.y & 0xffffu));
            acc[3] += a * bf2f((bf16_t)(pk.y >> 16));
        }
    }
    {
        const uint2* zp = (const uint2*)(z + (size_t)NN * 256);
        float erh = head ? er11 : er10;
        float fmh = fin_m[2 + head], fih = fin_inv[2 + head];
        for (int jj = w; jj < deg1; jj += 4) {
            int s;
            float a;
            if (jj < CAP) {
                s = ss[1][jj];
                a = se[1][2 * jj + head];
            } else {
                s = srcc1[beg1 + jj];
                float2 ev = ((const float2*)el1)[s];
                a = __expf(lrelu((head ? ev.y : ev.x) + erh) - fmh) * fih;
            }
            uint2 pk = zp[s * 64 + lane];
            acc[0] += a * bf2f((bf16_t)(pk.x & 0xffffu));
            acc[1] += a * bf2f((bf16_t)(pk.x >> 16));
            acc[2] += a * bf2f((bf16_t)(pk.y & 0xffffu));
            acc[3] += a * bf2f((bf16_t)(pk.y >> 16));
        }
    }
#pragma unroll
    for (int k = 0; k < 4; ++k) sh[w][lane * 4 + k] = acc[k];   // idx = h*128+o
    __syncthreads();
    if (t < 128) {
        float v = bc2[t];
#pragma unroll
        for (int ww = 0; ww < 4; ++ww) v += sh[ww][t] + sh[ww][128 + t];
        if (*flagp) ((float*)out)[(size_t)d * 128 + t] = v;
        else        ((bf16_t*)out)[(size_t)d * 128 + t] = f2bf(v);
    }
}

extern "C" void kernel_launch(void* const* d_in, const int* in_sizes, int n_in,
                              void* d_out, int out_size, void* d_ws, size_t ws_size,
                              hipStream_t stream) {
    (void)in_sizes; (void)n_in; (void)out_size; (void)ws_size;
    const void* x0 = d_in[0];
    const int* src0 = (const int*)d_in[1];
    const int* dst0 = (const int*)d_in[2];
    const int* src1 = (const int*)d_in[3];
    const int* dst1 = (const int*)d_in[4];

    char* ws = (char*)d_ws;
    size_t off = 0;
    auto alloc = [&](size_t bytes) -> void* {
        void* p = ws + off;
        off = (off + bytes + 255) & ~(size_t)255;
        return p;
    };
    int* flag = (int*)alloc(4);
    // weight tensors (16, x excluded): W1_0,al,ar,b | W1_1,... | W2_0,... | W2_1,...
    static const int tn[NTC] = {128 * 512, 512, 512, 512,
                                128 * 512, 512, 512, 512,
                                256 * 256, 256, 256, 256,
                                256 * 256, 256, 256, 256};
    bf16_t* tb[NTC];
    for (int i = 0; i < NTC; ++i) tb[i] = (bf16_t*)alloc((size_t)tn[i] * 2);

    bf16_t* Wc1f = (bf16_t*)alloc((size_t)512 * 256 * 2);
    bf16_t* Wzf  = (bf16_t*)alloc((size_t)2 * 65536 * 2);
    float* wal1 = (float*)alloc(512 * 4);
    float* war1 = (float*)alloc(512 * 4);
    float* wal2 = (float*)alloc(1024 * 4);
    float* war2 = (float*)alloc(1024 * 4);
    float* bc1  = (float*)alloc(256 * 4);
    float* bc2  = (float*)alloc(128 * 4);

    // zero region: cnt0, cnt1, el2/er2 (atomic targets)
    char* zbeg = ws + off;
    int* cnt0 = (int*)alloc(NN * 4);
    int* cnt1 = (int*)alloc(NN * 4);
    float* el2_0 = (float*)alloc(NN * 2 * 4);
    float* er2_0 = (float*)alloc(NN * 2 * 4);
    float* el2_1 = (float*)alloc(NN * 2 * 4);
    float* er2_1 = (float*)alloc(NN * 2 * 4);
    char* zend = ws + off;
    int zcount = (int)((zend - zbeg) >> 2);

    int* offs0 = (int*)alloc((NN + 1) * 4);
    int* offs1 = (int*)alloc((NN + 1) * 4);
    int* cur0  = (int*)alloc(NN * 4);
    int* cur1  = (int*)alloc(NN * 4);
    int* srcc0 = (int*)alloc(NE * 4);
    int* srcc1 = (int*)alloc(NE * 4);
    float* el1_0 = (float*)alloc(NN * 2 * 4);
    float* er1_0 = (float*)alloc(NN * 2 * 4);
    float* el1_1 = (float*)alloc(NN * 2 * 4);
    float* er1_1 = (float*)alloc(NN * 2 * 4);
    bf16_t* h1 = (bf16_t*)alloc((size_t)NN * 256 * 2);
    bf16_t* Y  = (bf16_t*)alloc((size_t)NN * 1024 * 2);  // y1 [N,512]; later z [2][N,256]
    bf16_t* y1 = Y;
    bf16_t* z  = Y;   // safe: gemmZ writes z after gemm1 finished reading y1

    // ---- 1. convert weights + zero + inline dtype detect ----
    CzArgs cz;
    static const int din_idx[NTC] = {5, 6, 7, 8, 9, 10, 11, 12,
                                     13, 14, 15, 16, 17, 18, 19, 20};
    int total_blocks = 0;
    for (int i = 0; i < NTC; ++i) {
        cz.src[i] = d_in[din_idx[i]];
        cz.dst[i] = tb[i];
        cz.n[i] = tn[i];
        cz.nblk[i] = (tn[i] + 255) / 256;
        total_blocks += cz.nblk[i];
    }
    cz.zero_ptr = (int*)zbeg;
    cz.zn = zcount;
    cz.nblk[NTC] = (zcount + 255) / 256;
    total_blocks += cz.nblk[NTC];
    cz.xsrc = (const unsigned*)x0;
    cz.flag_out = flag;
    convzero_kernel<<<total_blocks, 256, 0, stream>>>(cz);

    // ---- 2. prep + hist ----
    PhArgs ph;
    ph.p.W1[0] = tb[0];  ph.p.W1[1] = tb[4];
    ph.p.W2[0] = tb[8];  ph.p.W2[1] = tb[12];
    ph.p.al1[0] = tb[1]; ph.p.ar1[0] = tb[2];
    ph.p.al1[1] = tb[5]; ph.p.ar1[1] = tb[6];
    ph.p.al2[0] = tb[9]; ph.p.ar2[0] = tb[10];
    ph.p.al2[1] = tb[13]; ph.p.ar2[1] = tb[14];
    ph.p.b1[0] = tb[3];  ph.p.b1[1] = tb[7];
    ph.p.b2[0] = tb[11]; ph.p.b2[1] = tb[15];
    ph.p.wal1 = wal1; ph.p.war1 = war1;
    ph.p.wal2 = wal2; ph.p.war2 = war2;
    ph.p.bc1 = bc1; ph.p.bc2 = bc2;
    ph.p.Wc1f = Wc1f; ph.p.Wzf = Wzf;
    ph.c.src[0] = src0; ph.c.src[1] = src1;
    ph.c.dst[0] = dst0; ph.c.dst[1] = dst1;
    ph.c.cnt[0] = cnt0; ph.c.cnt[1] = cnt1;
    ph.c.offs[0] = offs0; ph.c.offs[1] = offs1;
    ph.c.cursor[0] = cur0; ph.c.cursor[1] = cur1;
    ph.c.srcc[0] = srcc0; ph.c.srcc[1] = srcc1;
    prep_hist_kernel<<<142 + 2500, 256, 0, stream>>>(ph);

    // ---- 3. scan ----
    scan2_kernel<<<2, 256, 0, stream>>>(ph.c, NN);

    // ---- 4. scatter + elr1 (dual-path x) ----
    scat_elr_kernel<<<5000 + 2500, 256, 0, stream>>>(
        ph.c, x0, flag, wal1, war1, el1_0, er1_0, el1_1, er1_1);

    // ---- 5. agg1: gather x rows -> y1[N,512] ----
    agg1_kernel<<<NN, 256, 0, stream>>>(offs0, srcc0, el1_0, er1_0,
                                        offs1, srcc1, el1_1, er1_1, x0, flag, y1);

    // ---- 6. gemm1 -> h1, el2/er2 ----
    gemm1_kernel<<<dim3(4, 313), 256, 0, stream>>>(
        y1, Wc1f, bc1, h1, wal2, war2, el2_0, er2_0, el2_1, er2_1, NN);

    // ---- 7. gemmZ: z_rel = h1 @ (0.5*W2_rel) ----
    gemmz_kernel<<<dim3(4, 313, 2), 256, 0, stream>>>(h1, Wzf, z, NN);

    // ---- 8. aggout: gather z rows -> d_out ----
    aggout_kernel<<<NN, 256, 0, stream>>>(offs0, srcc0, el2_0, er2_0,
                                          offs1, srcc1, el2_1, er2_1,
                                          z, bc2, d_out, flag);
}

// Round 10
// 399.224 us; speedup vs baseline: 1.5235x; 1.0714x over previous
//
#include <hip/hip_runtime.h>

// RGAT: 2-layer, 2-relation GAT. N=20000, E=320000/rel, D=128, H=2.
// Round 10: (1) agg gather loops 2-way unrolled (2 independent gathers in
// flight per wave -> latency hiding); (2) gemm1/gemmZ use 8 col-frags/wave,
// grid.x halved (redundant A traffic halved). Structure otherwise round-9.

#define NN 20000
#define NE 320000

typedef unsigned short bf16_t;
typedef __attribute__((ext_vector_type(8))) short short8;
typedef __attribute__((ext_vector_type(4))) float f32x4;

__device__ __forceinline__ float bf2f(bf16_t u) {
    return __uint_as_float(((unsigned)u) << 16);
}
__device__ __forceinline__ bf16_t f2bf(float f) {
    unsigned x = __float_as_uint(f);
    unsigned r = (x + 0x7fffu + ((x >> 16) & 1u)) >> 16;   // RNE
    return (bf16_t)r;
}
__device__ __forceinline__ float lrelu(float v) {
    return (v > 0.f) ? v : 0.2f * v;
}
__device__ __forceinline__ void load_x2(const void* x, int flag, int idx,
                                        float& v0, float& v1) {
    if (flag) {
        float2 f = ((const float2*)x)[idx];
        v0 = f.x; v1 = f.y;
    } else {
        unsigned pk = ((const unsigned*)x)[idx];
        v0 = bf2f((bf16_t)(pk & 0xffffu));
        v1 = bf2f((bf16_t)(pk >> 16));
    }
}

// ------------- convert 16 float tensors (weights) to bf16 + zero region -----
#define NTC 16
struct CzArgs {
    const void* src[NTC];
    bf16_t* dst[NTC];
    int n[NTC];
    int nblk[NTC + 1];
    int* zero_ptr;
    int zn;
    const unsigned* xsrc;
    int* flag_out;
};
__global__ void convzero_kernel(CzArgs a) {
    __shared__ int fl_s;
    int t = threadIdx.x;
    if (t < 64) {
        float mx = 0.f;
        for (int i = t; i < 256; i += 64) {
            float v = fabsf(bf2f((bf16_t)(a.xsrc[i] & 0xffffu)));
            v = (v <= 1e30f) ? v : 1e30f;
            mx = fmaxf(mx, v);
        }
        for (int off = 32; off > 0; off >>= 1) mx = fmaxf(mx, __shfl_xor(mx, off));
        if (t == 0) {
            int f = (mx > 1e6f) ? 1 : 0;
            fl_s = f;
            if (blockIdx.x == 0) *a.flag_out = f;
        }
    }
    __syncthreads();
    int flag = fl_s;
    int b = blockIdx.x;
    int ti = 0;
#pragma unroll 1
    for (; ti <= NTC; ++ti) {
        if (b < a.nblk[ti]) break;
        b -= a.nblk[ti];
    }
    int i = b * 256 + t;
    if (ti < NTC) {
        if (i < a.n[ti]) {
            if (flag) a.dst[ti][i] = f2bf(((const float*)a.src[ti])[i]);
            else      a.dst[ti][i] = ((const bf16_t*)a.src[ti])[i];
        }
    } else {
        if (i < a.zn) a.zero_ptr[i] = 0;
    }
}

// ---------------- prep: wal/war vectors, biases, frag repacks ----------------
struct PrepArgs {
    const bf16_t *W1[2], *W2[2];
    const bf16_t *al1[2], *ar1[2], *al2[2], *ar2[2];
    const bf16_t *b1[2], *b2[2];
    float *wal1, *war1;     // [2rel*2h*128]
    float *wal2, *war2;     // [2rel*2h*256]
    float *bc1, *bc2;       // [256], [128]
    bf16_t *Wc1f;           // combined layer-1 weight, frag order (K=512,M=256)
    bf16_t *Wzf;            // per-rel 0.5*W2 frag tables (K=256,M=256) x2
};
// bx: [0,4) wal1/war1 | [4,12) wal2/war2 | [12,14) bc | [14,78) Wc1f | [78,142) Wzf
__device__ __forceinline__ void prep_body(const PrepArgs& p, int bx, int tid) {
    if (bx < 4) {
        int t = bx * 256 + tid;
        int lr = t >> 9, rel = (t >> 8) & 1, h = (t >> 7) & 1, k = t & 127;
        const bf16_t* av = lr ? p.ar1[rel] : p.al1[rel];
        const bf16_t* W = p.W1[rel];
        float s = 0.f;
        for (int o = 0; o < 256; ++o)
            s += bf2f(W[k * 512 + h * 256 + o]) * bf2f(av[h * 256 + o]);
        (lr ? p.war1 : p.wal1)[(rel * 2 + h) * 128 + k] = s;
    } else if (bx < 12) {
        int t = (bx - 4) * 256 + tid;
        int lr = t >> 10, rel = (t >> 9) & 1, h = (t >> 8) & 1, k = t & 255;
        const bf16_t* av = lr ? p.ar2[rel] : p.al2[rel];
        const bf16_t* W = p.W2[rel];
        float s = 0.f;
        for (int o = 0; o < 128; ++o)
            s += bf2f(W[k * 256 + h * 128 + o]) * bf2f(av[h * 128 + o]);
        (lr ? p.war2 : p.wal2)[(rel * 2 + h) * 256 + k] = s;
    } else if (bx < 14) {
        int t = (bx - 12) * 256 + tid;
        if (t < 256) {
            p.bc1[t] = 0.5f * (bf2f(p.b1[0][t]) + bf2f(p.b1[0][256 + t]) +
                               bf2f(p.b1[1][t]) + bf2f(p.b1[1][256 + t]));
        } else if (t < 384) {
            int o = t - 256;
            p.bc2[o] = 0.5f * (bf2f(p.b2[0][o]) + bf2f(p.b2[0][128 + o]) +
                               bf2f(p.b2[1][o]) + bf2f(p.b2[1][128 + o]));
        }
    } else if (bx < 78) {               // Wc1f: K=512, M=256, KS=16
        int i = (bx - 14) * 256 + tid;
        int lane = i & 63;
        int t2 = i >> 6;
        int ct = t2 >> 4, ks = t2 & 15;
        int col = ct * 16 + (lane & 15);
        bf16_t* out = p.Wc1f + (size_t)i * 8;
#pragma unroll
        for (int j = 0; j < 8; ++j) {
            int r = ks * 32 + ((lane >> 4) << 3) + j;
            int rel = r >> 8, h = (r >> 7) & 1, kx = r & 127;
            out[j] = f2bf(0.5f * bf2f(p.W1[rel][kx * 512 + h * 256 + col]));
        }
    } else {                            // Wzf: per rel K=256, M=256, KS=8
        int b = bx - 78;
        int rel = b >> 5;
        int i = (b & 31) * 256 + tid;
        int lane = i & 63;
        int t2 = i >> 6;
        int ct = t2 >> 3, ks = t2 & 7;
        int col = ct * 16 + (lane & 15);
        bf16_t* out = p.Wzf + (size_t)rel * 65536 + (size_t)i * 8;
#pragma unroll
        for (int j = 0; j < 8; ++j) {
            int r = ks * 32 + ((lane >> 4) << 3) + j;
            out[j] = f2bf(0.5f * bf2f(p.W2[rel][r * 256 + col]));
        }
    }
}

// ---------------- CSR build ----------------
struct Csr2 {
    const int* src[2];
    const int* dst[2];
    int* cnt[2];
    int* offs[2];
    int* cursor[2];
    int* srcc[2];
};
struct PhArgs { PrepArgs p; Csr2 c; };
__global__ void prep_hist_kernel(PhArgs a) {
    int bx = blockIdx.x;
    if (bx < 142) {
        prep_body(a.p, bx, threadIdx.x);
    } else {
        int b = bx - 142;
        int rel = b / 1250;
        int i = (b - rel * 1250) * 256 + threadIdx.x;
        if (i < NE) atomicAdd(&a.c.cnt[rel][a.c.dst[rel][i]], 1);
    }
}

__global__ void scan2_kernel(Csr2 c, int n) {
    int rel = blockIdx.x;
    const int* cnt = c.cnt[rel];
    int* offs = c.offs[rel];
    int* cursor = c.cursor[rel];
    __shared__ int sums[256];
    int t = threadIdx.x;
    int chunk = (n + 255) >> 8;
    int lo = t * chunk;
    int hi = min(lo + chunk, n);
    int s = 0;
    for (int i = lo; i < hi; ++i) s += cnt[i];
    sums[t] = s;
    __syncthreads();
    if (t == 0) {
        int run = 0;
        for (int i = 0; i < 256; ++i) { int v = sums[i]; sums[i] = run; run += v; }
    }
    __syncthreads();
    int run = sums[t];
    for (int i = lo; i < hi; ++i) { int v = cnt[i]; offs[i] = run; cursor[i] = run; run += v; }
    if (t == 255) offs[n] = run;
}

// merged: elr1 (5000 blocks, dual-path x) + scatter (2x1250 blocks)
__global__ void scat_elr_kernel(Csr2 c, const void* __restrict__ x,
                                const int* __restrict__ flagp,
                                const float* __restrict__ wal1,
                                const float* __restrict__ war1,
                                float* __restrict__ el0, float* __restrict__ er0,
                                float* __restrict__ el1, float* __restrict__ er1) {
    __shared__ float wl[512], wr[512];
    int t = threadIdx.x;
    if (blockIdx.x < 5000) {
        wl[t] = wal1[t]; wl[t + 256] = wal1[t + 256];
        wr[t] = war1[t]; wr[t + 256] = war1[t + 256];
        __syncthreads();
        int fl = *flagp;
        int w = t >> 6, lane = t & 63;
        int node = blockIdx.x * 4 + w;
        float v0, v1;
        load_x2(x, fl, node * 64 + lane, v0, v1);
        float de[4], dr[4];
#pragma unroll
        for (int cch = 0; cch < 4; ++cch) {
            de[cch] = v0 * wl[cch * 128 + 2 * lane] + v1 * wl[cch * 128 + 2 * lane + 1];
            dr[cch] = v0 * wr[cch * 128 + 2 * lane] + v1 * wr[cch * 128 + 2 * lane + 1];
        }
#pragma unroll
        for (int off = 32; off > 0; off >>= 1) {
#pragma unroll
            for (int cch = 0; cch < 4; ++cch) {
                de[cch] += __shfl_xor(de[cch], off);
                dr[cch] += __shfl_xor(dr[cch], off);
            }
        }
        if (lane == 0) {
            el0[node * 2 + 0] = de[0]; el0[node * 2 + 1] = de[1];
            el1[node * 2 + 0] = de[2]; el1[node * 2 + 1] = de[3];
            er0[node * 2 + 0] = dr[0]; er0[node * 2 + 1] = dr[1];
            er1[node * 2 + 0] = dr[2]; er1[node * 2 + 1] = dr[3];
        }
    } else {
        int b = blockIdx.x - 5000;
        int rel = b / 1250;
        int i = (b - rel * 1250) * 256 + t;
        if (i < NE) {
            int p = atomicAdd(&c.cursor[rel][c.dst[rel][i]], 1);
            c.srcc[rel][p] = c.src[rel][i];
        }
    }
}

// ---------------- agg1: softmax + gather x rows -> y1[N,512] ----------------
// gather loop 2-way unrolled (2 independent x-row loads in flight per wave)
__global__ void agg1_kernel(
    const int* __restrict__ offs0, const int* __restrict__ srcc0,
    const float* __restrict__ el0, const float* __restrict__ er0,
    const int* __restrict__ offs1, const int* __restrict__ srcc1,
    const float* __restrict__ el1, const float* __restrict__ er1,
    const void* __restrict__ x, const int* __restrict__ flagp,
    bf16_t* __restrict__ y1) {
    constexpr int CAP = 64;
    __shared__ float sh[4][512];
    __shared__ int   ss[2][CAP];
    __shared__ float se[2][2 * CAP];
    __shared__ float fin_m[4], fin_inv[4];
    int d = blockIdx.x;
    int t = threadIdx.x;
    int w = t >> 6, lane = t & 63;
    int beg0 = offs0[d], deg0 = offs0[d + 1] - beg0;
    int beg1 = offs1[d], deg1 = offs1[d + 1] - beg1;
    int c0 = min(deg0, CAP), c1 = min(deg1, CAP);
    float er00 = er0[d * 2], er01 = er0[d * 2 + 1];
    float er10 = er1[d * 2], er11 = er1[d * 2 + 1];

    for (int j = t; j < c0; j += 256) {
        int s = srcc0[beg0 + j];
        ss[0][j] = s;
        float2 ev = ((const float2*)el0)[s];
        se[0][2 * j] = lrelu(ev.x + er00);
        se[0][2 * j + 1] = lrelu(ev.y + er01);
    }
    for (int j = t; j < c1; j += 256) {
        int s = srcc1[beg1 + j];
        ss[1][j] = s;
        float2 ev = ((const float2*)el1)[s];
        se[1][2 * j] = lrelu(ev.x + er10);
        se[1][2 * j + 1] = lrelu(ev.y + er11);
    }
    __syncthreads();
    if (w < 2) {
        int rel = w;
        int head = lane & 1;
        int cc = rel ? c1 : c0;
        int deg = rel ? deg1 : deg0;
        int beg = rel ? beg1 : beg0;
        const int* sc = rel ? srcc1 : srcc0;
        const float* elp = rel ? el1 : el0;
        float erh = rel ? (head ? er11 : er10) : (head ? er01 : er00);
        float m = -1e30f, s = 0.f;
        for (int j = lane >> 1; j < cc; j += 32) {
            float e = se[rel][2 * j + head];
            float mn = fmaxf(m, e);
            s = s * __expf(m - mn) + __expf(e - mn);
            m = mn;
        }
        for (int j = cc + (lane >> 1); j < deg; j += 32) {
            int sv = sc[beg + j];
            float e = lrelu(elp[sv * 2 + head] + erh);
            float mn = fmaxf(m, e);
            s = s * __expf(m - mn) + __expf(e - mn);
            m = mn;
        }
#pragma unroll
        for (int off = 2; off < 64; off <<= 1) {
            float om = __shfl_xor(m, off);
            float os = __shfl_xor(s, off);
            float mn = fmaxf(m, om);
            s = s * __expf(m - mn) + os * __expf(om - mn);
            m = mn;
        }
        if (lane < 2) {
            fin_m[rel * 2 + head] = m;
            fin_inv[rel * 2 + head] = 1.f / fmaxf(s, 1e-9f);
        }
    }
    __syncthreads();
    for (int i = t; i < 2 * c0; i += 256)
        se[0][i] = __expf(se[0][i] - fin_m[i & 1]) * fin_inv[i & 1];
    for (int i = t; i < 2 * c1; i += 256)
        se[1][i] = __expf(se[1][i] - fin_m[2 + (i & 1)]) * fin_inv[2 + (i & 1)];
    __syncthreads();

    int fl = *flagp;
    float a00 = 0.f, a01 = 0.f, a10 = 0.f, a11 = 0.f;
    float b00 = 0.f, b01 = 0.f, b10 = 0.f, b11 = 0.f;
    {
        auto get0 = [&](int jj, int& s, float& p0, float& p1) {
            if (jj < CAP) {
                s = ss[0][jj];
                p0 = se[0][2 * jj];
                p1 = se[0][2 * jj + 1];
            } else {
                s = srcc0[beg0 + jj];
                float2 ev = ((const float2*)el0)[s];
                p0 = __expf(lrelu(ev.x + er00) - fin_m[0]) * fin_inv[0];
                p1 = __expf(lrelu(ev.y + er01) - fin_m[1]) * fin_inv[1];
            }
        };
        int jj = w;
        for (; jj + 4 < deg0; jj += 8) {
            int sA, sB;
            float pA0, pA1, pB0, pB1;
            get0(jj, sA, pA0, pA1);
            get0(jj + 4, sB, pB0, pB1);
            float vA0, vA1, vB0, vB1;
            load_x2(x, fl, sA * 64 + lane, vA0, vA1);
            load_x2(x, fl, sB * 64 + lane, vB0, vB1);
            a00 += pA0 * vA0 + pB0 * vB0;
            a01 += pA0 * vA1 + pB0 * vB1;
            a10 += pA1 * vA0 + pB1 * vB0;
            a11 += pA1 * vA1 + pB1 * vB1;
        }
        if (jj < deg0) {
            int sA;
            float pA0, pA1;
            get0(jj, sA, pA0, pA1);
            float vA0, vA1;
            load_x2(x, fl, sA * 64 + lane, vA0, vA1);
            a00 += pA0 * vA0; a01 += pA0 * vA1;
            a10 += pA1 * vA0; a11 += pA1 * vA1;
        }
    }
    {
        auto get1 = [&](int jj, int& s, float& p0, float& p1) {
            if (jj < CAP) {
                s = ss[1][jj];
                p0 = se[1][2 * jj];
                p1 = se[1][2 * jj + 1];
            } else {
                s = srcc1[beg1 + jj];
                float2 ev = ((const float2*)el1)[s];
                p0 = __expf(lrelu(ev.x + er10) - fin_m[2]) * fin_inv[2];
                p1 = __expf(lrelu(ev.y + er11) - fin_m[3]) * fin_inv[3];
            }
        };
        int jj = w;
        for (; jj + 4 < deg1; jj += 8) {
            int sA, sB;
            float pA0, pA1, pB0, pB1;
            get1(jj, sA, pA0, pA1);
            get1(jj + 4, sB, pB0, pB1);
            float vA0, vA1, vB0, vB1;
            load_x2(x, fl, sA * 64 + lane, vA0, vA1);
            load_x2(x, fl, sB * 64 + lane, vB0, vB1);
            b00 += pA0 * vA0 + pB0 * vB0;
            b01 += pA0 * vA1 + pB0 * vB1;
            b10 += pA1 * vA0 + pB1 * vB0;
            b11 += pA1 * vA1 + pB1 * vB1;
        }
        if (jj < deg1) {
            int sA;
            float pA0, pA1;
            get1(jj, sA, pA0, pA1);
            float vA0, vA1;
            load_x2(x, fl, sA * 64 + lane, vA0, vA1);
            b00 += pA0 * vA0; b01 += pA0 * vA1;
            b10 += pA1 * vA0; b11 += pA1 * vA1;
        }
    }
    sh[w][0 + 2 * lane] = a00;       sh[w][0 + 2 * lane + 1] = a01;
    sh[w][128 + 2 * lane] = a10;     sh[w][128 + 2 * lane + 1] = a11;
    sh[w][256 + 2 * lane] = b00;     sh[w][256 + 2 * lane + 1] = b01;
    sh[w][384 + 2 * lane] = b10;     sh[w][384 + 2 * lane + 1] = b11;
    __syncthreads();
#pragma unroll
    for (int rep = 0; rep < 2; ++rep) {
        int o = t + rep * 256;
        float v = sh[0][o] + sh[1][o] + sh[2][o] + sh[3][o];
        y1[(size_t)d * 512 + o] = f2bf(v);
    }
}

// -------- gemm1: h1 = relu(y1 @ Wc1 + bc1); 8 col-frags/wave; el2/er2 -------
__global__ void gemm1_kernel(const bf16_t* __restrict__ A, const bf16_t* __restrict__ Wf,
                             const float* __restrict__ bc1, bf16_t* __restrict__ h1,
                             const float* __restrict__ wal2, const float* __restrict__ war2,
                             float* __restrict__ el2_0, float* __restrict__ er2_0,
                             float* __restrict__ el2_1, float* __restrict__ er2_1,
                             int n) {
    constexpr int K = 512, M = 256, KS = 16, NF = 8;
    int w = threadIdx.x >> 6, lane = threadIdx.x & 63;
    int q = lane >> 4, m16 = lane & 15;
    int rf = blockIdx.y * 64 + w * 16;
    if (rf >= n) return;
    f32x4 acc[NF] = {};
    const bf16_t* Arow = A + (size_t)(rf + m16) * K + q * 8;
    for (int ks = 0; ks < KS; ++ks) {
        short8 af = *(const short8*)(Arow + ks * 32);
#pragma unroll
        for (int f = 0; f < NF; ++f) {
            int ct = blockIdx.x * NF + f;
            short8 bfr = *(const short8*)(Wf + ((size_t)(ct * KS + ks) * 64 + lane) * 8);
            acc[f] = __builtin_amdgcn_mfma_f32_16x16x32_bf16(af, bfr, acc[f], 0, 0, 0);
        }
    }
    int col0 = blockIdx.x * (NF * 16);
    float del[2][2][4] = {};
    float der[2][2][4] = {};
#pragma unroll
    for (int f = 0; f < NF; ++f) {
        int col = col0 + f * 16 + m16;
        float bcv = bc1[col];
        float wle[2][2], wre[2][2];
#pragma unroll
        for (int rel = 0; rel < 2; ++rel)
#pragma unroll
            for (int h = 0; h < 2; ++h) {
                wle[rel][h] = wal2[(rel * 2 + h) * 256 + col];
                wre[rel][h] = war2[(rel * 2 + h) * 256 + col];
            }
#pragma unroll
        for (int r = 0; r < 4; ++r) {
            int row = rf + q * 4 + r;
            float v = fmaxf(acc[f][r] + bcv, 0.f);
            bf16_t hb = f2bf(v);
            h1[(size_t)row * M + col] = hb;
            float vb = bf2f(hb);
#pragma unroll
            for (int rel = 0; rel < 2; ++rel)
#pragma unroll
                for (int h = 0; h < 2; ++h) {
                    del[rel][h][r] += vb * wle[rel][h];
                    der[rel][h][r] += vb * wre[rel][h];
                }
        }
    }
#pragma unroll
    for (int off = 1; off < 16; off <<= 1) {
#pragma unroll
        for (int rel = 0; rel < 2; ++rel)
#pragma unroll
            for (int h = 0; h < 2; ++h)
#pragma unroll
                for (int r = 0; r < 4; ++r) {
                    del[rel][h][r] += __shfl_xor(del[rel][h][r], off);
                    der[rel][h][r] += __shfl_xor(der[rel][h][r], off);
                }
    }
    if (m16 == 0) {
#pragma unroll
        for (int r = 0; r < 4; ++r) {
            int row = rf + q * 4 + r;
            atomicAdd(&el2_0[row * 2 + 0], del[0][0][r]);
            atomicAdd(&el2_0[row * 2 + 1], del[0][1][r]);
            atomicAdd(&el2_1[row * 2 + 0], del[1][0][r]);
            atomicAdd(&el2_1[row * 2 + 1], del[1][1][r]);
            atomicAdd(&er2_0[row * 2 + 0], der[0][0][r]);
            atomicAdd(&er2_0[row * 2 + 1], der[0][1][r]);
            atomicAdd(&er2_1[row * 2 + 0], der[1][0][r]);
            atomicAdd(&er2_1[row * 2 + 1], der[1][1][r]);
        }
    }
}

// -------- gemmZ: z_rel = h1 @ (0.5*W2_rel); 8 col-frags/wave, grid.z=2 ------
__global__ void gemmz_kernel(const bf16_t* __restrict__ A, const bf16_t* __restrict__ Wzf,
                             bf16_t* __restrict__ z, int n) {
    constexpr int K = 256, M = 256, KS = 8, NF = 8;
    int rel = blockIdx.z;
    const bf16_t* Wf = Wzf + (size_t)rel * 65536;
    bf16_t* C = z + (size_t)rel * NN * 256;
    int w = threadIdx.x >> 6, lane = threadIdx.x & 63;
    int q = lane >> 4, m16 = lane & 15;
    int rf = blockIdx.y * 64 + w * 16;
    if (rf >= n) return;
    f32x4 acc[NF] = {};
    const bf16_t* Arow = A + (size_t)(rf + m16) * K + q * 8;
    for (int ks = 0; ks < KS; ++ks) {
        short8 af = *(const short8*)(Arow + ks * 32);
#pragma unroll
        for (int f = 0; f < NF; ++f) {
            int ct = blockIdx.x * NF + f;
            short8 bfr = *(const short8*)(Wf + ((size_t)(ct * KS + ks) * 64 + lane) * 8);
            acc[f] = __builtin_amdgcn_mfma_f32_16x16x32_bf16(af, bfr, acc[f], 0, 0, 0);
        }
    }
    int col0 = blockIdx.x * (NF * 16);
#pragma unroll
    for (int f = 0; f < NF; ++f) {
#pragma unroll
        for (int r = 0; r < 4; ++r) {
            int row = rf + q * 4 + r;
            C[(size_t)row * M + col0 + f * 16 + m16] = f2bf(acc[f][r]);
        }
    }
}

// -------- aggout: softmax + gather z rows -> out[N,128]; 2-way unrolled -----
__global__ void aggout_kernel(
    const int* __restrict__ offs0, const int* __restrict__ srcc0,
    const float* __restrict__ el0, const float* __restrict__ er0,
    const int* __restrict__ offs1, const int* __restrict__ srcc1,
    const float* __restrict__ el1, const float* __restrict__ er1,
    const bf16_t* __restrict__ z, const float* __restrict__ bc2,
    void* __restrict__ out, const int* __restrict__ flagp) {
    constexpr int CAP = 64;
    __shared__ float sh[4][256];
    __shared__ int   ss[2][CAP];
    __shared__ float se[2][2 * CAP];
    __shared__ float fin_m[4], fin_inv[4];
    int d = blockIdx.x;
    int t = threadIdx.x;
    int w = t >> 6, lane = t & 63;
    int beg0 = offs0[d], deg0 = offs0[d + 1] - beg0;
    int beg1 = offs1[d], deg1 = offs1[d + 1] - beg1;
    int c0 = min(deg0, CAP), c1 = min(deg1, CAP);
    float er00 = er0[d * 2], er01 = er0[d * 2 + 1];
    float er10 = er1[d * 2], er11 = er1[d * 2 + 1];

    for (int j = t; j < c0; j += 256) {
        int s = srcc0[beg0 + j];
        ss[0][j] = s;
        float2 ev = ((const float2*)el0)[s];
        se[0][2 * j] = lrelu(ev.x + er00);
        se[0][2 * j + 1] = lrelu(ev.y + er01);
    }
    for (int j = t; j < c1; j += 256) {
        int s = srcc1[beg1 + j];
        ss[1][j] = s;
        float2 ev = ((const float2*)el1)[s];
        se[1][2 * j] = lrelu(ev.x + er10);
        se[1][2 * j + 1] = lrelu(ev.y + er11);
    }
    __syncthreads();
    if (w < 2) {
        int rel = w;
        int head = lane & 1;
        int cc = rel ? c1 : c0;
        int deg = rel ? deg1 : deg0;
        int beg = rel ? beg1 : beg0;
        const int* sc = rel ? srcc1 : srcc0;
        const float* elp = rel ? el1 : el0;
        float erh = rel ? (head ? er11 : er10) : (head ? er01 : er00);
        float m = -1e30f, s = 0.f;
        for (int j = lane >> 1; j < cc; j += 32) {
            float e = se[rel][2 * j + head];
            float mn = fmaxf(m, e);
            s = s * __expf(m - mn) + __expf(e - mn);
            m = mn;
        }
        for (int j = cc + (lane >> 1); j < deg; j += 32) {
            int sv = sc[beg + j];
            float e = lrelu(elp[sv * 2 + head] + erh);
            float mn = fmaxf(m, e);
            s = s * __expf(m - mn) + __expf(e - mn);
            m = mn;
        }
#pragma unroll
        for (int off = 2; off < 64; off <<= 1) {
            float om = __shfl_xor(m, off);
            float os = __shfl_xor(s, off);
            float mn = fmaxf(m, om);
            s = s * __expf(m - mn) + os * __expf(om - mn);
            m = mn;
        }
        if (lane < 2) {
            fin_m[rel * 2 + head] = m;
            fin_inv[rel * 2 + head] = 1.f / fmaxf(s, 1e-9f);
        }
    }
    __syncthreads();
    for (int i = t; i < 2 * c0; i += 256)
        se[0][i] = __expf(se[0][i] - fin_m[i & 1]) * fin_inv[i & 1];
    for (int i = t; i < 2 * c1; i += 256)
        se[1][i] = __expf(se[1][i] - fin_m[2 + (i & 1)]) * fin_inv[2 + (i & 1)];
    __syncthreads();

    int head = lane >> 5;                 // lanes 0-31 head 0, 32-63 head 1
    float acc[4] = {};
    {
        const uint2* zp = (const uint2*)z;
        float erh = head ? er01 : er00;
        float fmh = fin_m[head], fih = fin_inv[head];
        auto get0 = [&](int jj, int& s, float& a) {
            if (jj < CAP) {
                s = ss[0][jj];
                a = se[0][2 * jj + head];
            } else {
                s = srcc0[beg0 + jj];
                float2 ev = ((const float2*)el0)[s];
                a = __expf(lrelu((head ? ev.y : ev.x) + erh) - fmh) * fih;
            }
        };
        int jj = w;
        for (; jj + 4 < deg0; jj += 8) {
            int sA, sB;
            float aA, aB;
            get0(jj, sA, aA);
            get0(jj + 4, sB, aB);
            uint2 pkA = zp[sA * 64 + lane];
            uint2 pkB = zp[sB * 64 + lane];
            acc[0] += aA * bf2f((bf16_t)(pkA.x & 0xffffu)) + aB * bf2f((bf16_t)(pkB.x & 0xffffu));
            acc[1] += aA * bf2f((bf16_t)(pkA.x >> 16)) + aB * bf2f((bf16_t)(pkB.x >> 16));
            acc[2] += aA * bf2f((bf16_t)(pkA.y & 0xffffu)) + aB * bf2f((bf16_t)(pkB.y & 0xffffu));
            acc[3] += aA * bf2f((bf16_t)(pkA.y >> 16)) + aB * bf2f((bf16_t)(pkB.y >> 16));
        }
        if (jj < deg0) {
            int sA;
            float aA;
            get0(jj, sA, aA);
            uint2 pk = zp[sA * 64 + lane];
            acc[0] += aA * bf2f((bf16_t)(pk.x & 0xffffu));
            acc[1] += aA * bf2f((bf16_t)(pk.x >> 16));
            acc[2] += aA * bf2f((bf16_t)(pk.y & 0xffffu));
            acc[3] += aA * bf2f((bf16_t)(pk.y >> 16));
        }
    }
    {
        const uint2* zp = (const uint2*)(z + (size_t)NN * 256);
        float erh = head ? er11 : er10;
        float fmh = fin_m[2 + head], fih = fin_inv[2 + head];
        auto get1 = [&](int jj, int& s, float& a) {
            if (jj < CAP) {
                s = ss[1][jj];
                a = se[1][2 * jj + head];
            } else {
                s = srcc1[beg1 + jj];
                float2 ev = ((const float2*)el1)[s];
                a = __expf(lrelu((head ? ev.y : ev.x) + erh) - fmh) * fih;
            }
        };
        int jj = w;
        for (; jj + 4 < deg1; jj += 8) {
            int sA, sB;
            float aA, aB;
            get1(jj, sA, aA);
            get1(jj + 4, sB, aB);
            uint2 pkA = zp[sA * 64 + lane];
            uint2 pkB = zp[sB * 64 + lane];
            acc[0] += aA * bf2f((bf16_t)(pkA.x & 0xffffu)) + aB * bf2f((bf16_t)(pkB.x & 0xffffu));
            acc[1] += aA * bf2f((bf16_t)(pkA.x >> 16)) + aB * bf2f((bf16_t)(pkB.x >> 16));
            acc[2] += aA * bf2f((bf16_t)(pkA.y & 0xffffu)) + aB * bf2f((bf16_t)(pkB.y & 0xffffu));
            acc[3] += aA * bf2f((bf16_t)(pkA.y >> 16)) + aB * bf2f((bf16_t)(pkB.y >> 16));
        }
        if (jj < deg1) {
            int sA;
            float aA;
            get1(jj, sA, aA);
            uint2 pk = zp[sA * 64 + lane];
            acc[0] += aA * bf2f((bf16_t)(pk.x & 0xffffu));
            acc[1] += aA * bf2f((bf16_t)(pk.x >> 16));
            acc[2] += aA * bf2f((bf16_t)(pk.y & 0xffffu));
            acc[3] += aA * bf2f((bf16_t)(pk.y >> 16));
        }
    }
#pragma unroll
    for (int k = 0; k < 4; ++k) sh[w][lane * 4 + k] = acc[k];   // idx = h*128+o
    __syncthreads();
    if (t < 128) {
        float v = bc2[t];
#pragma unroll
        for (int ww = 0; ww < 4; ++ww) v += sh[ww][t] + sh[ww][128 + t];
        if (*flagp) ((float*)out)[(size_t)d * 128 + t] = v;
        else        ((bf16_t*)out)[(size_t)d * 128 + t] = f2bf(v);
    }
}

extern "C" void kernel_launch(void* const* d_in, const int* in_sizes, int n_in,
                              void* d_out, int out_size, void* d_ws, size_t ws_size,
                              hipStream_t stream) {
    (void)in_sizes; (void)n_in; (void)out_size; (void)ws_size;
    const void* x0 = d_in[0];
    const int* src0 = (const int*)d_in[1];
    const int* dst0 = (const int*)d_in[2];
    const int* src1 = (const int*)d_in[3];
    const int* dst1 = (const int*)d_in[4];

    char* ws = (char*)d_ws;
    size_t off = 0;
    auto alloc = [&](size_t bytes) -> void* {
        void* p = ws + off;
        off = (off + bytes + 255) & ~(size_t)255;
        return p;
    };
    int* flag = (int*)alloc(4);
    static const int tn[NTC] = {128 * 512, 512, 512, 512,
                                128 * 512, 512, 512, 512,
                                256 * 256, 256, 256, 256,
                                256 * 256, 256, 256, 256};
    bf16_t* tb[NTC];
    for (int i = 0; i < NTC; ++i) tb[i] = (bf16_t*)alloc((size_t)tn[i] * 2);

    bf16_t* Wc1f = (bf16_t*)alloc((size_t)512 * 256 * 2);
    bf16_t* Wzf  = (bf16_t*)alloc((size_t)2 * 65536 * 2);
    float* wal1 = (float*)alloc(512 * 4);
    float* war1 = (float*)alloc(512 * 4);
    float* wal2 = (float*)alloc(1024 * 4);
    float* war2 = (float*)alloc(1024 * 4);
    float* bc1  = (float*)alloc(256 * 4);
    float* bc2  = (float*)alloc(128 * 4);

    char* zbeg = ws + off;
    int* cnt0 = (int*)alloc(NN * 4);
    int* cnt1 = (int*)alloc(NN * 4);
    float* el2_0 = (float*)alloc(NN * 2 * 4);
    float* er2_0 = (float*)alloc(NN * 2 * 4);
    float* el2_1 = (float*)alloc(NN * 2 * 4);
    float* er2_1 = (float*)alloc(NN * 2 * 4);
    char* zend = ws + off;
    int zcount = (int)((zend - zbeg) >> 2);

    int* offs0 = (int*)alloc((NN + 1) * 4);
    int* offs1 = (int*)alloc((NN + 1) * 4);
    int* cur0  = (int*)alloc(NN * 4);
    int* cur1  = (int*)alloc(NN * 4);
    int* srcc0 = (int*)alloc(NE * 4);
    int* srcc1 = (int*)alloc(NE * 4);
    float* el1_0 = (float*)alloc(NN * 2 * 4);
    float* er1_0 = (float*)alloc(NN * 2 * 4);
    float* el1_1 = (float*)alloc(NN * 2 * 4);
    float* er1_1 = (float*)alloc(NN * 2 * 4);
    bf16_t* h1 = (bf16_t*)alloc((size_t)NN * 256 * 2);
    bf16_t* Y  = (bf16_t*)alloc((size_t)NN * 1024 * 2);  // y1 [N,512]; later z [2][N,256]
    bf16_t* y1 = Y;
    bf16_t* z  = Y;   // safe: gemmZ writes z after gemm1 finished reading y1

    // ---- 1. convert weights + zero + inline dtype detect ----
    CzArgs cz;
    static const int din_idx[NTC] = {5, 6, 7, 8, 9, 10, 11, 12,
                                     13, 14, 15, 16, 17, 18, 19, 20};
    int total_blocks = 0;
    for (int i = 0; i < NTC; ++i) {
        cz.src[i] = d_in[din_idx[i]];
        cz.dst[i] = tb[i];
        cz.n[i] = tn[i];
        cz.nblk[i] = (tn[i] + 255) / 256;
        total_blocks += cz.nblk[i];
    }
    cz.zero_ptr = (int*)zbeg;
    cz.zn = zcount;
    cz.nblk[NTC] = (zcount + 255) / 256;
    total_blocks += cz.nblk[NTC];
    cz.xsrc = (const unsigned*)x0;
    cz.flag_out = flag;
    convzero_kernel<<<total_blocks, 256, 0, stream>>>(cz);

    // ---- 2. prep + hist ----
    PhArgs ph;
    ph.p.W1[0] = tb[0];  ph.p.W1[1] = tb[4];
    ph.p.W2[0] = tb[8];  ph.p.W2[1] = tb[12];
    ph.p.al1[0] = tb[1]; ph.p.ar1[0] = tb[2];
    ph.p.al1[1] = tb[5]; ph.p.ar1[1] = tb[6];
    ph.p.al2[0] = tb[9]; ph.p.ar2[0] = tb[10];
    ph.p.al2[1] = tb[13]; ph.p.ar2[1] = tb[14];
    ph.p.b1[0] = tb[3];  ph.p.b1[1] = tb[7];
    ph.p.b2[0] = tb[11]; ph.p.b2[1] = tb[15];
    ph.p.wal1 = wal1; ph.p.war1 = war1;
    ph.p.wal2 = wal2; ph.p.war2 = war2;
    ph.p.bc1 = bc1; ph.p.bc2 = bc2;
    ph.p.Wc1f = Wc1f; ph.p.Wzf = Wzf;
    ph.c.src[0] = src0; ph.c.src[1] = src1;
    ph.c.dst[0] = dst0; ph.c.dst[1] = dst1;
    ph.c.cnt[0] = cnt0; ph.c.cnt[1] = cnt1;
    ph.c.offs[0] = offs0; ph.c.offs[1] = offs1;
    ph.c.cursor[0] = cur0; ph.c.cursor[1] = cur1;
    ph.c.srcc[0] = srcc0; ph.c.srcc[1] = srcc1;
    prep_hist_kernel<<<142 + 2500, 256, 0, stream>>>(ph);

    // ---- 3. scan ----
    scan2_kernel<<<2, 256, 0, stream>>>(ph.c, NN);

    // ---- 4. scatter + elr1 (dual-path x) ----
    scat_elr_kernel<<<5000 + 2500, 256, 0, stream>>>(
        ph.c, x0, flag, wal1, war1, el1_0, er1_0, el1_1, er1_1);

    // ---- 5. agg1: gather x rows -> y1[N,512] ----
    agg1_kernel<<<NN, 256, 0, stream>>>(offs0, srcc0, el1_0, er1_0,
                                        offs1, srcc1, el1_1, er1_1, x0, flag, y1);

    // ---- 6. gemm1 -> h1, el2/er2 ----
    gemm1_kernel<<<dim3(2, 313), 256, 0, stream>>>(
        y1, Wc1f, bc1, h1, wal2, war2, el2_0, er2_0, el2_1, er2_1, NN);

    // ---- 7. gemmZ: z_rel = h1 @ (0.5*W2_rel) ----
    gemmz_kernel<<<dim3(2, 313, 2), 256, 0, stream>>>(h1, Wzf, z, NN);

    // ---- 8. aggout: gather z rows -> d_out ----
    aggout_kernel<<<NN, 256, 0, stream>>>(offs0, srcc0, el2_0, er2_0,
                                          offs1, srcc1, el2_1, er2_1,
                                          z, bc2, d_out, flag);
}

// Round 11
// 392.304 us; speedup vs baseline: 1.5504x; 1.0176x over previous
//
#include <hip/hip_runtime.h>

// RGAT: 2-layer, 2-relation GAT. N=20000, E=320000/rel, D=128, H=2.
// Round 11: agg gather loops 4-way unrolled (4 independent gathers in flight
// per wave). Structure otherwise identical to round 10 (399 us).

#define NN 20000
#define NE 320000

typedef unsigned short bf16_t;
typedef __attribute__((ext_vector_type(8))) short short8;
typedef __attribute__((ext_vector_type(4))) float f32x4;

__device__ __forceinline__ float bf2f(bf16_t u) {
    return __uint_as_float(((unsigned)u) << 16);
}
__device__ __forceinline__ bf16_t f2bf(float f) {
    unsigned x = __float_as_uint(f);
    unsigned r = (x + 0x7fffu + ((x >> 16) & 1u)) >> 16;   // RNE
    return (bf16_t)r;
}
__device__ __forceinline__ float lrelu(float v) {
    return (v > 0.f) ? v : 0.2f * v;
}
__device__ __forceinline__ void load_x2(const void* x, int flag, int idx,
                                        float& v0, float& v1) {
    if (flag) {
        float2 f = ((const float2*)x)[idx];
        v0 = f.x; v1 = f.y;
    } else {
        unsigned pk = ((const unsigned*)x)[idx];
        v0 = bf2f((bf16_t)(pk & 0xffffu));
        v1 = bf2f((bf16_t)(pk >> 16));
    }
}

// ------------- convert 16 float tensors (weights) to bf16 + zero region -----
#define NTC 16
struct CzArgs {
    const void* src[NTC];
    bf16_t* dst[NTC];
    int n[NTC];
    int nblk[NTC + 1];
    int* zero_ptr;
    int zn;
    const unsigned* xsrc;
    int* flag_out;
};
__global__ void convzero_kernel(CzArgs a) {
    __shared__ int fl_s;
    int t = threadIdx.x;
    if (t < 64) {
        float mx = 0.f;
        for (int i = t; i < 256; i += 64) {
            float v = fabsf(bf2f((bf16_t)(a.xsrc[i] & 0xffffu)));
            v = (v <= 1e30f) ? v : 1e30f;
            mx = fmaxf(mx, v);
        }
        for (int off = 32; off > 0; off >>= 1) mx = fmaxf(mx, __shfl_xor(mx, off));
        if (t == 0) {
            int f = (mx > 1e6f) ? 1 : 0;
            fl_s = f;
            if (blockIdx.x == 0) *a.flag_out = f;
        }
    }
    __syncthreads();
    int flag = fl_s;
    int b = blockIdx.x;
    int ti = 0;
#pragma unroll 1
    for (; ti <= NTC; ++ti) {
        if (b < a.nblk[ti]) break;
        b -= a.nblk[ti];
    }
    int i = b * 256 + t;
    if (ti < NTC) {
        if (i < a.n[ti]) {
            if (flag) a.dst[ti][i] = f2bf(((const float*)a.src[ti])[i]);
            else      a.dst[ti][i] = ((const bf16_t*)a.src[ti])[i];
        }
    } else {
        if (i < a.zn) a.zero_ptr[i] = 0;
    }
}

// ---------------- prep: wal/war vectors, biases, frag repacks ----------------
struct PrepArgs {
    const bf16_t *W1[2], *W2[2];
    const bf16_t *al1[2], *ar1[2], *al2[2], *ar2[2];
    const bf16_t *b1[2], *b2[2];
    float *wal1, *war1;     // [2rel*2h*128]
    float *wal2, *war2;     // [2rel*2h*256]
    float *bc1, *bc2;       // [256], [128]
    bf16_t *Wc1f;           // combined layer-1 weight, frag order (K=512,M=256)
    bf16_t *Wzf;            // per-rel 0.5*W2 frag tables (K=256,M=256) x2
};
// bx: [0,4) wal1/war1 | [4,12) wal2/war2 | [12,14) bc | [14,78) Wc1f | [78,142) Wzf
__device__ __forceinline__ void prep_body(const PrepArgs& p, int bx, int tid) {
    if (bx < 4) {
        int t = bx * 256 + tid;
        int lr = t >> 9, rel = (t >> 8) & 1, h = (t >> 7) & 1, k = t & 127;
        const bf16_t* av = lr ? p.ar1[rel] : p.al1[rel];
        const bf16_t* W = p.W1[rel];
        float s = 0.f;
        for (int o = 0; o < 256; ++o)
            s += bf2f(W[k * 512 + h * 256 + o]) * bf2f(av[h * 256 + o]);
        (lr ? p.war1 : p.wal1)[(rel * 2 + h) * 128 + k] = s;
    } else if (bx < 12) {
        int t = (bx - 4) * 256 + tid;
        int lr = t >> 10, rel = (t >> 9) & 1, h = (t >> 8) & 1, k = t & 255;
        const bf16_t* av = lr ? p.ar2[rel] : p.al2[rel];
        const bf16_t* W = p.W2[rel];
        float s = 0.f;
        for (int o = 0; o < 128; ++o)
            s += bf2f(W[k * 256 + h * 128 + o]) * bf2f(av[h * 128 + o]);
        (lr ? p.war2 : p.wal2)[(rel * 2 + h) * 256 + k] = s;
    } else if (bx < 14) {
        int t = (bx - 12) * 256 + tid;
        if (t < 256) {
            p.bc1[t] = 0.5f * (bf2f(p.b1[0][t]) + bf2f(p.b1[0][256 + t]) +
                               bf2f(p.b1[1][t]) + bf2f(p.b1[1][256 + t]));
        } else if (t < 384) {
            int o = t - 256;
            p.bc2[o] = 0.5f * (bf2f(p.b2[0][o]) + bf2f(p.b2[0][128 + o]) +
                               bf2f(p.b2[1][o]) + bf2f(p.b2[1][128 + o]));
        }
    } else if (bx < 78) {               // Wc1f: K=512, M=256, KS=16
        int i = (bx - 14) * 256 + tid;
        int lane = i & 63;
        int t2 = i >> 6;
        int ct = t2 >> 4, ks = t2 & 15;
        int col = ct * 16 + (lane & 15);
        bf16_t* out = p.Wc1f + (size_t)i * 8;
#pragma unroll
        for (int j = 0; j < 8; ++j) {
            int r = ks * 32 + ((lane >> 4) << 3) + j;
            int rel = r >> 8, h = (r >> 7) & 1, kx = r & 127;
            out[j] = f2bf(0.5f * bf2f(p.W1[rel][kx * 512 + h * 256 + col]));
        }
    } else {                            // Wzf: per rel K=256, M=256, KS=8
        int b = bx - 78;
        int rel = b >> 5;
        int i = (b & 31) * 256 + tid;
        int lane = i & 63;
        int t2 = i >> 6;
        int ct = t2 >> 3, ks = t2 & 7;
        int col = ct * 16 + (lane & 15);
        bf16_t* out = p.Wzf + (size_t)rel * 65536 + (size_t)i * 8;
#pragma unroll
        for (int j = 0; j < 8; ++j) {
            int r = ks * 32 + ((lane >> 4) << 3) + j;
            out[j] = f2bf(0.5f * bf2f(p.W2[rel][r * 256 + col]));
        }
    }
}

// ---------------- CSR build ----------------
struct Csr2 {
    const int* src[2];
    const int* dst[2];
    int* cnt[2];
    int* offs[2];
    int* cursor[2];
    int* srcc[2];
};
struct PhArgs { PrepArgs p; Csr2 c; };
__global__ void prep_hist_kernel(PhArgs a) {
    int bx = blockIdx.x;
    if (bx < 142) {
        prep_body(a.p, bx, threadIdx.x);
    } else {
        int b = bx - 142;
        int rel = b / 1250;
        int i = (b - rel * 1250) * 256 + threadIdx.x;
        if (i < NE) atomicAdd(&a.c.cnt[rel][a.c.dst[rel][i]], 1);
    }
}

__global__ void scan2_kernel(Csr2 c, int n) {
    int rel = blockIdx.x;
    const int* cnt = c.cnt[rel];
    int* offs = c.offs[rel];
    int* cursor = c.cursor[rel];
    __shared__ int sums[256];
    int t = threadIdx.x;
    int chunk = (n + 255) >> 8;
    int lo = t * chunk;
    int hi = min(lo + chunk, n);
    int s = 0;
    for (int i = lo; i < hi; ++i) s += cnt[i];
    sums[t] = s;
    __syncthreads();
    if (t == 0) {
        int run = 0;
        for (int i = 0; i < 256; ++i) { int v = sums[i]; sums[i] = run; run += v; }
    }
    __syncthreads();
    int run = sums[t];
    for (int i = lo; i < hi; ++i) { int v = cnt[i]; offs[i] = run; cursor[i] = run; run += v; }
    if (t == 255) offs[n] = run;
}

// merged: elr1 (5000 blocks, dual-path x) + scatter (2x1250 blocks)
__global__ void scat_elr_kernel(Csr2 c, const void* __restrict__ x,
                                const int* __restrict__ flagp,
                                const float* __restrict__ wal1,
                                const float* __restrict__ war1,
                                float* __restrict__ el0, float* __restrict__ er0,
                                float* __restrict__ el1, float* __restrict__ er1) {
    __shared__ float wl[512], wr[512];
    int t = threadIdx.x;
    if (blockIdx.x < 5000) {
        wl[t] = wal1[t]; wl[t + 256] = wal1[t + 256];
        wr[t] = war1[t]; wr[t + 256] = war1[t + 256];
        __syncthreads();
        int fl = *flagp;
        int w = t >> 6, lane = t & 63;
        int node = blockIdx.x * 4 + w;
        float v0, v1;
        load_x2(x, fl, node * 64 + lane, v0, v1);
        float de[4], dr[4];
#pragma unroll
        for (int cch = 0; cch < 4; ++cch) {
            de[cch] = v0 * wl[cch * 128 + 2 * lane] + v1 * wl[cch * 128 + 2 * lane + 1];
            dr[cch] = v0 * wr[cch * 128 + 2 * lane] + v1 * wr[cch * 128 + 2 * lane + 1];
        }
#pragma unroll
        for (int off = 32; off > 0; off >>= 1) {
#pragma unroll
            for (int cch = 0; cch < 4; ++cch) {
                de[cch] += __shfl_xor(de[cch], off);
                dr[cch] += __shfl_xor(dr[cch], off);
            }
        }
        if (lane == 0) {
            el0[node * 2 + 0] = de[0]; el0[node * 2 + 1] = de[1];
            el1[node * 2 + 0] = de[2]; el1[node * 2 + 1] = de[3];
            er0[node * 2 + 0] = dr[0]; er0[node * 2 + 1] = dr[1];
            er1[node * 2 + 0] = dr[2]; er1[node * 2 + 1] = dr[3];
        }
    } else {
        int b = blockIdx.x - 5000;
        int rel = b / 1250;
        int i = (b - rel * 1250) * 256 + t;
        if (i < NE) {
            int p = atomicAdd(&c.cursor[rel][c.dst[rel][i]], 1);
            c.srcc[rel][p] = c.src[rel][i];
        }
    }
}

// ---------------- agg1: softmax + gather x rows -> y1[N,512] ----------------
// gather loop 4-way unrolled (4 independent x-row loads in flight per wave)
__global__ void agg1_kernel(
    const int* __restrict__ offs0, const int* __restrict__ srcc0,
    const float* __restrict__ el0, const float* __restrict__ er0,
    const int* __restrict__ offs1, const int* __restrict__ srcc1,
    const float* __restrict__ el1, const float* __restrict__ er1,
    const void* __restrict__ x, const int* __restrict__ flagp,
    bf16_t* __restrict__ y1) {
    constexpr int CAP = 64;
    __shared__ float sh[4][512];
    __shared__ int   ss[2][CAP];
    __shared__ float se[2][2 * CAP];
    __shared__ float fin_m[4], fin_inv[4];
    int d = blockIdx.x;
    int t = threadIdx.x;
    int w = t >> 6, lane = t & 63;
    int beg0 = offs0[d], deg0 = offs0[d + 1] - beg0;
    int beg1 = offs1[d], deg1 = offs1[d + 1] - beg1;
    int c0 = min(deg0, CAP), c1 = min(deg1, CAP);
    float er00 = er0[d * 2], er01 = er0[d * 2 + 1];
    float er10 = er1[d * 2], er11 = er1[d * 2 + 1];

    for (int j = t; j < c0; j += 256) {
        int s = srcc0[beg0 + j];
        ss[0][j] = s;
        float2 ev = ((const float2*)el0)[s];
        se[0][2 * j] = lrelu(ev.x + er00);
        se[0][2 * j + 1] = lrelu(ev.y + er01);
    }
    for (int j = t; j < c1; j += 256) {
        int s = srcc1[beg1 + j];
        ss[1][j] = s;
        float2 ev = ((const float2*)el1)[s];
        se[1][2 * j] = lrelu(ev.x + er10);
        se[1][2 * j + 1] = lrelu(ev.y + er11);
    }
    __syncthreads();
    if (w < 2) {
        int rel = w;
        int head = lane & 1;
        int cc = rel ? c1 : c0;
        int deg = rel ? deg1 : deg0;
        int beg = rel ? beg1 : beg0;
        const int* sc = rel ? srcc1 : srcc0;
        const float* elp = rel ? el1 : el0;
        float erh = rel ? (head ? er11 : er10) : (head ? er01 : er00);
        float m = -1e30f, s = 0.f;
        for (int j = lane >> 1; j < cc; j += 32) {
            float e = se[rel][2 * j + head];
            float mn = fmaxf(m, e);
            s = s * __expf(m - mn) + __expf(e - mn);
            m = mn;
        }
        for (int j = cc + (lane >> 1); j < deg; j += 32) {
            int sv = sc[beg + j];
            float e = lrelu(elp[sv * 2 + head] + erh);
            float mn = fmaxf(m, e);
            s = s * __expf(m - mn) + __expf(e - mn);
            m = mn;
        }
#pragma unroll
        for (int off = 2; off < 64; off <<= 1) {
            float om = __shfl_xor(m, off);
            float os = __shfl_xor(s, off);
            float mn = fmaxf(m, om);
            s = s * __expf(m - mn) + os * __expf(om - mn);
            m = mn;
        }
        if (lane < 2) {
            fin_m[rel * 2 + head] = m;
            fin_inv[rel * 2 + head] = 1.f / fmaxf(s, 1e-9f);
        }
    }
    __syncthreads();
    for (int i = t; i < 2 * c0; i += 256)
        se[0][i] = __expf(se[0][i] - fin_m[i & 1]) * fin_inv[i & 1];
    for (int i = t; i < 2 * c1; i += 256)
        se[1][i] = __expf(se[1][i] - fin_m[2 + (i & 1)]) * fin_inv[2 + (i & 1)];
    __syncthreads();

    int fl = *flagp;
    float a00 = 0.f, a01 = 0.f, a10 = 0.f, a11 = 0.f;
    float b00 = 0.f, b01 = 0.f, b10 = 0.f, b11 = 0.f;
    {
        auto get0 = [&](int jj, int& s, float& p0, float& p1) {
            if (jj < CAP) {
                s = ss[0][jj];
                p0 = se[0][2 * jj];
                p1 = se[0][2 * jj + 1];
            } else {
                s = srcc0[beg0 + jj];
                float2 ev = ((const float2*)el0)[s];
                p0 = __expf(lrelu(ev.x + er00) - fin_m[0]) * fin_inv[0];
                p1 = __expf(lrelu(ev.y + er01) - fin_m[1]) * fin_inv[1];
            }
        };
        int jj = w;
        for (; jj + 12 < deg0; jj += 16) {
            int sA, sB, sC, sD;
            float pA0, pA1, pB0, pB1, pC0, pC1, pD0, pD1;
            get0(jj, sA, pA0, pA1);
            get0(jj + 4, sB, pB0, pB1);
            get0(jj + 8, sC, pC0, pC1);
            get0(jj + 12, sD, pD0, pD1);
            float vA0, vA1, vB0, vB1, vC0, vC1, vD0, vD1;
            load_x2(x, fl, sA * 64 + lane, vA0, vA1);
            load_x2(x, fl, sB * 64 + lane, vB0, vB1);
            load_x2(x, fl, sC * 64 + lane, vC0, vC1);
            load_x2(x, fl, sD * 64 + lane, vD0, vD1);
            a00 += pA0 * vA0 + pB0 * vB0 + pC0 * vC0 + pD0 * vD0;
            a01 += pA0 * vA1 + pB0 * vB1 + pC0 * vC1 + pD0 * vD1;
            a10 += pA1 * vA0 + pB1 * vB0 + pC1 * vC0 + pD1 * vD0;
            a11 += pA1 * vA1 + pB1 * vB1 + pC1 * vC1 + pD1 * vD1;
        }
        for (; jj < deg0; jj += 4) {
            int sA;
            float pA0, pA1;
            get0(jj, sA, pA0, pA1);
            float vA0, vA1;
            load_x2(x, fl, sA * 64 + lane, vA0, vA1);
            a00 += pA0 * vA0; a01 += pA0 * vA1;
            a10 += pA1 * vA0; a11 += pA1 * vA1;
        }
    }
    {
        auto get1 = [&](int jj, int& s, float& p0, float& p1) {
            if (jj < CAP) {
                s = ss[1][jj];
                p0 = se[1][2 * jj];
                p1 = se[1][2 * jj + 1];
            } else {
                s = srcc1[beg1 + jj];
                float2 ev = ((const float2*)el1)[s];
                p0 = __expf(lrelu(ev.x + er10) - fin_m[2]) * fin_inv[2];
                p1 = __expf(lrelu(ev.y + er11) - fin_m[3]) * fin_inv[3];
            }
        };
        int jj = w;
        for (; jj + 12 < deg1; jj += 16) {
            int sA, sB, sC, sD;
            float pA0, pA1, pB0, pB1, pC0, pC1, pD0, pD1;
            get1(jj, sA, pA0, pA1);
            get1(jj + 4, sB, pB0, pB1);
            get1(jj + 8, sC, pC0, pC1);
            get1(jj + 12, sD, pD0, pD1);
            float vA0, vA1, vB0, vB1, vC0, vC1, vD0, vD1;
            load_x2(x, fl, sA * 64 + lane, vA0, vA1);
            load_x2(x, fl, sB * 64 + lane, vB0, vB1);
            load_x2(x, fl, sC * 64 + lane, vC0, vC1);
            load_x2(x, fl, sD * 64 + lane, vD0, vD1);
            b00 += pA0 * vA0 + pB0 * vB0 + pC0 * vC0 + pD0 * vD0;
            b01 += pA0 * vA1 + pB0 * vB1 + pC0 * vC1 + pD0 * vD1;
            b10 += pA1 * vA0 + pB1 * vB0 + pC1 * vC0 + pD1 * vD0;
            b11 += pA1 * vA1 + pB1 * vB1 + pC1 * vC1 + pD1 * vD1;
        }
        for (; jj < deg1; jj += 4) {
            int sA;
            float pA0, pA1;
            get1(jj, sA, pA0, pA1);
            float vA0, vA1;
            load_x2(x, fl, sA * 64 + lane, vA0, vA1);
            b00 += pA0 * vA0; b01 += pA0 * vA1;
            b10 += pA1 * vA0; b11 += pA1 * vA1;
        }
    }
    sh[w][0 + 2 * lane] = a00;       sh[w][0 + 2 * lane + 1] = a01;
    sh[w][128 + 2 * lane] = a10;     sh[w][128 + 2 * lane + 1] = a11;
    sh[w][256 + 2 * lane] = b00;     sh[w][256 + 2 * lane + 1] = b01;
    sh[w][384 + 2 * lane] = b10;     sh[w][384 + 2 * lane + 1] = b11;
    __syncthreads();
#pragma unroll
    for (int rep = 0; rep < 2; ++rep) {
        int o = t + rep * 256;
        float v = sh[0][o] + sh[1][o] + sh[2][o] + sh[3][o];
        y1[(size_t)d * 512 + o] = f2bf(v);
    }
}

// -------- gemm1: h1 = relu(y1 @ Wc1 + bc1); 8 col-frags/wave; el2/er2 -------
__global__ void gemm1_kernel(const bf16_t* __restrict__ A, const bf16_t* __restrict__ Wf,
                             const float* __restrict__ bc1, bf16_t* __restrict__ h1,
                             const float* __restrict__ wal2, const float* __restrict__ war2,
                             float* __restrict__ el2_0, float* __restrict__ er2_0,
                             float* __restrict__ el2_1, float* __restrict__ er2_1,
                             int n) {
    constexpr int K = 512, M = 256, KS = 16, NF = 8;
    int w = threadIdx.x >> 6, lane = threadIdx.x & 63;
    int q = lane >> 4, m16 = lane & 15;
    int rf = blockIdx.y * 64 + w * 16;
    if (rf >= n) return;
    f32x4 acc[NF] = {};
    const bf16_t* Arow = A + (size_t)(rf + m16) * K + q * 8;
    for (int ks = 0; ks < KS; ++ks) {
        short8 af = *(const short8*)(Arow + ks * 32);
#pragma unroll
        for (int f = 0; f < NF; ++f) {
            int ct = blockIdx.x * NF + f;
            short8 bfr = *(const short8*)(Wf + ((size_t)(ct * KS + ks) * 64 + lane) * 8);
            acc[f] = __builtin_amdgcn_mfma_f32_16x16x32_bf16(af, bfr, acc[f], 0, 0, 0);
        }
    }
    int col0 = blockIdx.x * (NF * 16);
    float del[2][2][4] = {};
    float der[2][2][4] = {};
#pragma unroll
    for (int f = 0; f < NF; ++f) {
        int col = col0 + f * 16 + m16;
        float bcv = bc1[col];
        float wle[2][2], wre[2][2];
#pragma unroll
        for (int rel = 0; rel < 2; ++rel)
#pragma unroll
            for (int h = 0; h < 2; ++h) {
                wle[rel][h] = wal2[(rel * 2 + h) * 256 + col];
                wre[rel][h] = war2[(rel * 2 + h) * 256 + col];
            }
#pragma unroll
        for (int r = 0; r < 4; ++r) {
            int row = rf + q * 4 + r;
            float v = fmaxf(acc[f][r] + bcv, 0.f);
            bf16_t hb = f2bf(v);
            h1[(size_t)row * M + col] = hb;
            float vb = bf2f(hb);
#pragma unroll
            for (int rel = 0; rel < 2; ++rel)
#pragma unroll
                for (int h = 0; h < 2; ++h) {
                    del[rel][h][r] += vb * wle[rel][h];
                    der[rel][h][r] += vb * wre[rel][h];
                }
        }
    }
#pragma unroll
    for (int off = 1; off < 16; off <<= 1) {
#pragma unroll
        for (int rel = 0; rel < 2; ++rel)
#pragma unroll
            for (int h = 0; h < 2; ++h)
#pragma unroll
                for (int r = 0; r < 4; ++r) {
                    del[rel][h][r] += __shfl_xor(del[rel][h][r], off);
                    der[rel][h][r] += __shfl_xor(der[rel][h][r], off);
                }
    }
    if (m16 == 0) {
#pragma unroll
        for (int r = 0; r < 4; ++r) {
            int row = rf + q * 4 + r;
            atomicAdd(&el2_0[row * 2 + 0], del[0][0][r]);
            atomicAdd(&el2_0[row * 2 + 1], del[0][1][r]);
            atomicAdd(&el2_1[row * 2 + 0], del[1][0][r]);
            atomicAdd(&el2_1[row * 2 + 1], del[1][1][r]);
            atomicAdd(&er2_0[row * 2 + 0], der[0][0][r]);
            atomicAdd(&er2_0[row * 2 + 1], der[0][1][r]);
            atomicAdd(&er2_1[row * 2 + 0], der[1][0][r]);
            atomicAdd(&er2_1[row * 2 + 1], der[1][1][r]);
        }
    }
}

// -------- gemmZ: z_rel = h1 @ (0.5*W2_rel); 8 col-frags/wave, grid.z=2 ------
__global__ void gemmz_kernel(const bf16_t* __restrict__ A, const bf16_t* __restrict__ Wzf,
                             bf16_t* __restrict__ z, int n) {
    constexpr int K = 256, M = 256, KS = 8, NF = 8;
    int rel = blockIdx.z;
    const bf16_t* Wf = Wzf + (size_t)rel * 65536;
    bf16_t* C = z + (size_t)rel * NN * 256;
    int w = threadIdx.x >> 6, lane = threadIdx.x & 63;
    int q = lane >> 4, m16 = lane & 15;
    int rf = blockIdx.y * 64 + w * 16;
    if (rf >= n) return;
    f32x4 acc[NF] = {};
    const bf16_t* Arow = A + (size_t)(rf + m16) * K + q * 8;
    for (int ks = 0; ks < KS; ++ks) {
        short8 af = *(const short8*)(Arow + ks * 32);
#pragma unroll
        for (int f = 0; f < NF; ++f) {
            int ct = blockIdx.x * NF + f;
            short8 bfr = *(const short8*)(Wf + ((size_t)(ct * KS + ks) * 64 + lane) * 8);
            acc[f] = __builtin_amdgcn_mfma_f32_16x16x32_bf16(af, bfr, acc[f], 0, 0, 0);
        }
    }
    int col0 = blockIdx.x * (NF * 16);
#pragma unroll
    for (int f = 0; f < NF; ++f) {
#pragma unroll
        for (int r = 0; r < 4; ++r) {
            int row = rf + q * 4 + r;
            C[(size_t)row * M + col0 + f * 16 + m16] = f2bf(acc[f][r]);
        }
    }
}

// -------- aggout: softmax + gather z rows -> out[N,128]; 4-way unrolled -----
__global__ void aggout_kernel(
    const int* __restrict__ offs0, const int* __restrict__ srcc0,
    const float* __restrict__ el0, const float* __restrict__ er0,
    const int* __restrict__ offs1, const int* __restrict__ srcc1,
    const float* __restrict__ el1, const float* __restrict__ er1,
    const bf16_t* __restrict__ z, const float* __restrict__ bc2,
    void* __restrict__ out, const int* __restrict__ flagp) {
    constexpr int CAP = 64;
    __shared__ float sh[4][256];
    __shared__ int   ss[2][CAP];
    __shared__ float se[2][2 * CAP];
    __shared__ float fin_m[4], fin_inv[4];
    int d = blockIdx.x;
    int t = threadIdx.x;
    int w = t >> 6, lane = t & 63;
    int beg0 = offs0[d], deg0 = offs0[d + 1] - beg0;
    int beg1 = offs1[d], deg1 = offs1[d + 1] - beg1;
    int c0 = min(deg0, CAP), c1 = min(deg1, CAP);
    float er00 = er0[d * 2], er01 = er0[d * 2 + 1];
    float er10 = er1[d * 2], er11 = er1[d * 2 + 1];

    for (int j = t; j < c0; j += 256) {
        int s = srcc0[beg0 + j];
        ss[0][j] = s;
        float2 ev = ((const float2*)el0)[s];
        se[0][2 * j] = lrelu(ev.x + er00);
        se[0][2 * j + 1] = lrelu(ev.y + er01);
    }
    for (int j = t; j < c1; j += 256) {
        int s = srcc1[beg1 + j];
        ss[1][j] = s;
        float2 ev = ((const float2*)el1)[s];
        se[1][2 * j] = lrelu(ev.x + er10);
        se[1][2 * j + 1] = lrelu(ev.y + er11);
    }
    __syncthreads();
    if (w < 2) {
        int rel = w;
        int head = lane & 1;
        int cc = rel ? c1 : c0;
        int deg = rel ? deg1 : deg0;
        int beg = rel ? beg1 : beg0;
        const int* sc = rel ? srcc1 : srcc0;
        const float* elp = rel ? el1 : el0;
        float erh = rel ? (head ? er11 : er10) : (head ? er01 : er00);
        float m = -1e30f, s = 0.f;
        for (int j = lane >> 1; j < cc; j += 32) {
            float e = se[rel][2 * j + head];
            float mn = fmaxf(m, e);
            s = s * __expf(m - mn) + __expf(e - mn);
            m = mn;
        }
        for (int j = cc + (lane >> 1); j < deg; j += 32) {
            int sv = sc[beg + j];
            float e = lrelu(elp[sv * 2 + head] + erh);
            float mn = fmaxf(m, e);
            s = s * __expf(m - mn) + __expf(e - mn);
            m = mn;
        }
#pragma unroll
        for (int off = 2; off < 64; off <<= 1) {
            float om = __shfl_xor(m, off);
            float os = __shfl_xor(s, off);
            float mn = fmaxf(m, om);
            s = s * __expf(m - mn) + os * __expf(om - mn);
            m = mn;
        }
        if (lane < 2) {
            fin_m[rel * 2 + head] = m;
            fin_inv[rel * 2 + head] = 1.f / fmaxf(s, 1e-9f);
        }
    }
    __syncthreads();
    for (int i = t; i < 2 * c0; i += 256)
        se[0][i] = __expf(se[0][i] - fin_m[i & 1]) * fin_inv[i & 1];
    for (int i = t; i < 2 * c1; i += 256)
        se[1][i] = __expf(se[1][i] - fin_m[2 + (i & 1)]) * fin_inv[2 + (i & 1)];
    __syncthreads();

    int head = lane >> 5;                 // lanes 0-31 head 0, 32-63 head 1
    float acc[4] = {};
    {
        const uint2* zp = (const uint2*)z;
        float erh = head ? er01 : er00;
        float fmh = fin_m[head], fih = fin_inv[head];
        auto get0 = [&](int jj, int& s, float& a) {
            if (jj < CAP) {
                s = ss[0][jj];
                a = se[0][2 * jj + head];
            } else {
                s = srcc0[beg0 + jj];
                float2 ev = ((const float2*)el0)[s];
                a = __expf(lrelu((head ? ev.y : ev.x) + erh) - fmh) * fih;
            }
        };
        int jj = w;
        for (; jj + 12 < deg0; jj += 16) {
            int sA, sB, sC, sD;
            float aA, aB, aC, aD;
            get0(jj, sA, aA);
            get0(jj + 4, sB, aB);
            get0(jj + 8, sC, aC);
            get0(jj + 12, sD, aD);
            uint2 pkA = zp[sA * 64 + lane];
            uint2 pkB = zp[sB * 64 + lane];
            uint2 pkC = zp[sC * 64 + lane];
            uint2 pkD = zp[sD * 64 + lane];
            acc[0] += aA * bf2f((bf16_t)(pkA.x & 0xffffu)) + aB * bf2f((bf16_t)(pkB.x & 0xffffu))
                    + aC * bf2f((bf16_t)(pkC.x & 0xffffu)) + aD * bf2f((bf16_t)(pkD.x & 0xffffu));
            acc[1] += aA * bf2f((bf16_t)(pkA.x >> 16)) + aB * bf2f((bf16_t)(pkB.x >> 16))
                    + aC * bf2f((bf16_t)(pkC.x >> 16)) + aD * bf2f((bf16_t)(pkD.x >> 16));
            acc[2] += aA * bf2f((bf16_t)(pkA.y & 0xffffu)) + aB * bf2f((bf16_t)(pkB.y & 0xffffu))
                    + aC * bf2f((bf16_t)(pkC.y & 0xffffu)) + aD * bf2f((bf16_t)(pkD.y & 0xffffu));
            acc[3] += aA * bf2f((bf16_t)(pkA.y >> 16)) + aB * bf2f((bf16_t)(pkB.y >> 16))
                    + aC * bf2f((bf16_t)(pkC.y >> 16)) + aD * bf2f((bf16_t)(pkD.y >> 16));
        }
        for (; jj < deg0; jj += 4) {
            int sA;
            float aA;
            get0(jj, sA, aA);
            uint2 pk = zp[sA * 64 + lane];
            acc[0] += aA * bf2f((bf16_t)(pk.x & 0xffffu));
            acc[1] += aA * bf2f((bf16_t)(pk.x >> 16));
            acc[2] += aA * bf2f((bf16_t)(pk.y & 0xffffu));
            acc[3] += aA * bf2f((bf16_t)(pk.y >> 16));
        }
    }
    {
        const uint2* zp = (const uint2*)(z + (size_t)NN * 256);
        float erh = head ? er11 : er10;
        float fmh = fin_m[2 + head], fih = fin_inv[2 + head];
        auto get1 = [&](int jj, int& s, float& a) {
            if (jj < CAP) {
                s = ss[1][jj];
                a = se[1][2 * jj + head];
            } else {
                s = srcc1[beg1 + jj];
                float2 ev = ((const float2*)el1)[s];
                a = __expf(lrelu((head ? ev.y : ev.x) + erh) - fmh) * fih;
            }
        };
        int jj = w;
        for (; jj + 12 < deg1; jj += 16) {
            int sA, sB, sC, sD;
            float aA, aB, aC, aD;
            get1(jj, sA, aA);
            get1(jj + 4, sB, aB);
            get1(jj + 8, sC, aC);
            get1(jj + 12, sD, aD);
            uint2 pkA = zp[sA * 64 + lane];
            uint2 pkB = zp[sB * 64 + lane];
            uint2 pkC = zp[sC * 64 + lane];
            uint2 pkD = zp[sD * 64 + lane];
            acc[0] += aA * bf2f((bf16_t)(pkA.x & 0xffffu)) + aB * bf2f((bf16_t)(pkB.x & 0xffffu))
                    + aC * bf2f((bf16_t)(pkC.x & 0xffffu)) + aD * bf2f((bf16_t)(pkD.x & 0xffffu));
            acc[1] += aA * bf2f((bf16_t)(pkA.x >> 16)) + aB * bf2f((bf16_t)(pkB.x >> 16))
                    + aC * bf2f((bf16_t)(pkC.x >> 16)) + aD * bf2f((bf16_t)(pkD.x >> 16));
            acc[2] += aA * bf2f((bf16_t)(pkA.y & 0xffffu)) + aB * bf2f((bf16_t)(pkB.y & 0xffffu))
                    + aC * bf2f((bf16_t)(pkC.y & 0xffffu)) + aD * bf2f((bf16_t)(pkD.y & 0xffffu));
            acc[3] += aA * bf2f((bf16_t)(pkA.y >> 16)) + aB * bf2f((bf16_t)(pkB.y >> 16))
                    + aC * bf2f((bf16_t)(pkC.y >> 16)) + aD * bf2f((bf16_t)(pkD.y >> 16));
        }
        for (; jj < deg1; jj += 4) {
            int sA;
            float aA;
            get1(jj, sA, aA);
            uint2 pk = zp[sA * 64 + lane];
            acc[0] += aA * bf2f((bf16_t)(pk.x & 0xffffu));
            acc[1] += aA * bf2f((bf16_t)(pk.x >> 16));
            acc[2] += aA * bf2f((bf16_t)(pk.y & 0xffffu));
            acc[3] += aA * bf2f((bf16_t)(pk.y >> 16));
        }
    }
#pragma unroll
    for (int k = 0; k < 4; ++k) sh[w][lane * 4 + k] = acc[k];   // idx = h*128+o
    __syncthreads();
    if (t < 128) {
        float v = bc2[t];
#pragma unroll
        for (int ww = 0; ww < 4; ++ww) v += sh[ww][t] + sh[ww][128 + t];
        if (*flagp) ((float*)out)[(size_t)d * 128 + t] = v;
        else        ((bf16_t*)out)[(size_t)d * 128 + t] = f2bf(v);
    }
}

extern "C" void kernel_launch(void* const* d_in, const int* in_sizes, int n_in,
                              void* d_out, int out_size, void* d_ws, size_t ws_size,
                              hipStream_t stream) {
    (void)in_sizes; (void)n_in; (void)out_size; (void)ws_size;
    const void* x0 = d_in[0];
    const int* src0 = (const int*)d_in[1];
    const int* dst0 = (const int*)d_in[2];
    const int* src1 = (const int*)d_in[3];
    const int* dst1 = (const int*)d_in[4];

    char* ws = (char*)d_ws;
    size_t off = 0;
    auto alloc = [&](size_t bytes) -> void* {
        void* p = ws + off;
        off = (off + bytes + 255) & ~(size_t)255;
        return p;
    };
    int* flag = (int*)alloc(4);
    static const int tn[NTC] = {128 * 512, 512, 512, 512,
                                128 * 512, 512, 512, 512,
                                256 * 256, 256, 256, 256,
                                256 * 256, 256, 256, 256};
    bf16_t* tb[NTC];
    for (int i = 0; i < NTC; ++i) tb[i] = (bf16_t*)alloc((size_t)tn[i] * 2);

    bf16_t* Wc1f = (bf16_t*)alloc((size_t)512 * 256 * 2);
    bf16_t* Wzf  = (bf16_t*)alloc((size_t)2 * 65536 * 2);
    float* wal1 = (float*)alloc(512 * 4);
    float* war1 = (float*)alloc(512 * 4);
    float* wal2 = (float*)alloc(1024 * 4);
    float* war2 = (float*)alloc(1024 * 4);
    float* bc1  = (float*)alloc(256 * 4);
    float* bc2  = (float*)alloc(128 * 4);

    char* zbeg = ws + off;
    int* cnt0 = (int*)alloc(NN * 4);
    int* cnt1 = (int*)alloc(NN * 4);
    float* el2_0 = (float*)alloc(NN * 2 * 4);
    float* er2_0 = (float*)alloc(NN * 2 * 4);
    float* el2_1 = (float*)alloc(NN * 2 * 4);
    float* er2_1 = (float*)alloc(NN * 2 * 4);
    char* zend = ws + off;
    int zcount = (int)((zend - zbeg) >> 2);

    int* offs0 = (int*)alloc((NN + 1) * 4);
    int* offs1 = (int*)alloc((NN + 1) * 4);
    int* cur0  = (int*)alloc(NN * 4);
    int* cur1  = (int*)alloc(NN * 4);
    int* srcc0 = (int*)alloc(NE * 4);
    int* srcc1 = (int*)alloc(NE * 4);
    float* el1_0 = (float*)alloc(NN * 2 * 4);
    float* er1_0 = (float*)alloc(NN * 2 * 4);
    float* el1_1 = (float*)alloc(NN * 2 * 4);
    float* er1_1 = (float*)alloc(NN * 2 * 4);
    bf16_t* h1 = (bf16_t*)alloc((size_t)NN * 256 * 2);
    bf16_t* Y  = (bf16_t*)alloc((size_t)NN * 1024 * 2);  // y1 [N,512]; later z [2][N,256]
    bf16_t* y1 = Y;
    bf16_t* z  = Y;   // safe: gemmZ writes z after gemm1 finished reading y1

    // ---- 1. convert weights + zero + inline dtype detect ----
    CzArgs cz;
    static const int din_idx[NTC] = {5, 6, 7, 8, 9, 10, 11, 12,
                                     13, 14, 15, 16, 17, 18, 19, 20};
    int total_blocks = 0;
    for (int i = 0; i < NTC; ++i) {
        cz.src[i] = d_in[din_idx[i]];
        cz.dst[i] = tb[i];
        cz.n[i] = tn[i];
        cz.nblk[i] = (tn[i] + 255) / 256;
        total_blocks += cz.nblk[i];
    }
    cz.zero_ptr = (int*)zbeg;
    cz.zn = zcount;
    cz.nblk[NTC] = (zcount + 255) / 256;
    total_blocks += cz.nblk[NTC];
    cz.xsrc = (const unsigned*)x0;
    cz.flag_out = flag;
    convzero_kernel<<<total_blocks, 256, 0, stream>>>(cz);

    // ---- 2. prep + hist ----
    PhArgs ph;
    ph.p.W1[0] = tb[0];  ph.p.W1[1] = tb[4];
    ph.p.W2[0] = tb[8];  ph.p.W2[1] = tb[12];
    ph.p.al1[0] = tb[1]; ph.p.ar1[0] = tb[2];
    ph.p.al1[1] = tb[5]; ph.p.ar1[1] = tb[6];
    ph.p.al2[0] = tb[9]; ph.p.ar2[0] = tb[10];
    ph.p.al2[1] = tb[13]; ph.p.ar2[1] = tb[14];
    ph.p.b1[0] = tb[3];  ph.p.b1[1] = tb[7];
    ph.p.b2[0] = tb[11]; ph.p.b2[1] = tb[15];
    ph.p.wal1 = wal1; ph.p.war1 = war1;
    ph.p.wal2 = wal2; ph.p.war2 = war2;
    ph.p.bc1 = bc1; ph.p.bc2 = bc2;
    ph.p.Wc1f = Wc1f; ph.p.Wzf = Wzf;
    ph.c.src[0] = src0; ph.c.src[1] = src1;
    ph.c.dst[0] = dst0; ph.c.dst[1] = dst1;
    ph.c.cnt[0] = cnt0; ph.c.cnt[1] = cnt1;
    ph.c.offs[0] = offs0; ph.c.offs[1] = offs1;
    ph.c.cursor[0] = cur0; ph.c.cursor[1] = cur1;
    ph.c.srcc[0] = srcc0; ph.c.srcc[1] = srcc1;
    prep_hist_kernel<<<142 + 2500, 256, 0, stream>>>(ph);

    // ---- 3. scan ----
    scan2_kernel<<<2, 256, 0, stream>>>(ph.c, NN);

    // ---- 4. scatter + elr1 (dual-path x) ----
    scat_elr_kernel<<<5000 + 2500, 256, 0, stream>>>(
        ph.c, x0, flag, wal1, war1, el1_0, er1_0, el1_1, er1_1);

    // ---- 5. agg1: gather x rows -> y1[N,512] ----
    agg1_kernel<<<NN, 256, 0, stream>>>(offs0, srcc0, el1_0, er1_0,
                                        offs1, srcc1, el1_1, er1_1, x0, flag, y1);

    // ---- 6. gemm1 -> h1, el2/er2 ----
    gemm1_kernel<<<dim3(2, 313), 256, 0, stream>>>(
        y1, Wc1f, bc1, h1, wal2, war2, el2_0, er2_0, el2_1, er2_1, NN);

    // ---- 7. gemmZ: z_rel = h1 @ (0.5*W2_rel) ----
    gemmz_kernel<<<dim3(2, 313, 2), 256, 0, stream>>>(h1, Wzf, z, NN);

    // ---- 8. aggout: gather z rows -> d_out ----
    aggout_kernel<<<NN, 256, 0, stream>>>(offs0, srcc0, el2_0, er2_0,
                                          offs1, srcc1, el2_1, er2_1,
                                          z, bc2, d_out, flag);
}